// Round 1
// baseline (6627.457 us; speedup 1.0000x reference)
//
#include <hip/hip_runtime.h>
#include <math.h>

#define S_    1024
#define D_    512
#define DI_   1024
#define DS_   16
#define KC_   4
#define E_    8
#define DFF_  2048
#define NTOK  2048     // B*S
#define VOCAB 32000
#define NCHUNK 16
#define CHL    64      // S_/NCHUNK

// ---------------- helpers ----------------
__device__ __forceinline__ float gelu_tanh(float x){
  float x3 = x*x*x;
  return 0.5f*x*(1.0f + tanhf(0.7978845608028654f*(x + 0.044715f*x3)));
}

// ---------------- embed: x = tok_emb[ids] + pos_emb ----------------
__global__ __launch_bounds__(128) void k_embed(const int* __restrict__ ids,
    const float* __restrict__ tok, const float* __restrict__ pos, float* __restrict__ x){
  int t  = blockIdx.x;
  int d4 = threadIdx.x << 2;
  int s  = t & (S_-1);
  int id = ids[t];
  float4 tv = *(const float4*)(tok + (size_t)id*D_ + d4);
  float4 pv = *(const float4*)(pos + (size_t)s*D_ + d4);
  float4 o; o.x=tv.x+pv.x; o.y=tv.y+pv.y; o.z=tv.z+pv.z; o.w=tv.w+pv.w;
  *(float4*)(x + (size_t)t*D_ + d4) = o;
}

// ---------------- rmsnorm (rows of D_=512), 128 threads ----------------
__global__ __launch_bounds__(128) void k_rmsnorm(const float* __restrict__ x,
    const float* __restrict__ w, float* __restrict__ out){
  int t = blockIdx.x;
  int d4 = threadIdx.x << 2;
  float4 v = *(const float4*)(x + (size_t)t*D_ + d4);
  float ss = v.x*v.x + v.y*v.y + v.z*v.z + v.w*v.w;
  #pragma unroll
  for (int off=32; off>=1; off>>=1) ss += __shfl_down(ss, off);
  __shared__ float sred[2];
  if ((threadIdx.x & 63) == 0) sred[threadIdx.x >> 6] = ss;
  __syncthreads();
  float total = sred[0] + sred[1];
  float scale = 1.0f / sqrtf(total * (1.0f/D_) + 1e-6f);
  float4 wv = *(const float4*)(w + d4);
  float4 o; o.x=v.x*scale*wv.x; o.y=v.y*scale*wv.y; o.z=v.z*scale*wv.z; o.w=v.w*scale*wv.w;
  *(float4*)(out + (size_t)t*D_ + d4) = o;
}

// ---------------- generic fp32 GEMM: C[M,N] = A[M,K] @ W[N,K]^T (+ epilogue) ----
// EPI 0: C = acc            (plain)
// EPI 1: C = gelu(acc+bias) (MoE w1 -> h)
// EPI 2: C += acc           (residual add)
// EPI 3: C += rowscale[row*E]* (acc + bias)   (MoE w2 accumulate; rowscale pre-offset by e)
template<int EPI>
__global__ __launch_bounds__(256) void gemm_f32(
    const float* __restrict__ A, const float* __restrict__ W,
    float* __restrict__ C, const float* __restrict__ bias,
    const float* __restrict__ rowscale, int M, int N, int K)
{
  __shared__ float As[16][128];
  __shared__ float Bs[16][128];
  const int tid  = threadIdx.x;
  const int row0 = blockIdx.x * 128;
  const int col0 = blockIdx.y * 128;
  const int tx = tid & 15, ty = tid >> 4;
  float acc[8][8];
  #pragma unroll
  for (int i=0;i<8;i++)
    #pragma unroll
    for (int j=0;j<8;j++) acc[i][j]=0.f;

  for (int kk=0; kk<K; kk+=16){
    #pragma unroll
    for (int it=0; it<2; ++it){
      int ci = tid + it*256;
      int r = ci >> 2, c4 = (ci & 3) << 2;
      float4 av = *(const float4*)(A + (size_t)(row0+r)*K + kk + c4);
      float4 wv = *(const float4*)(W + (size_t)(col0+r)*K + kk + c4);
      As[c4+0][r]=av.x; As[c4+1][r]=av.y; As[c4+2][r]=av.z; As[c4+3][r]=av.w;
      Bs[c4+0][r]=wv.x; Bs[c4+1][r]=wv.y; Bs[c4+2][r]=wv.z; Bs[c4+3][r]=wv.w;
    }
    __syncthreads();
    #pragma unroll
    for (int k=0;k<16;k++){
      float a8[8], b8[8];
      *(float4*)(a8)   = *(const float4*)(&As[k][ty*8]);
      *(float4*)(a8+4) = *(const float4*)(&As[k][ty*8+4]);
      *(float4*)(b8)   = *(const float4*)(&Bs[k][tx*8]);
      *(float4*)(b8+4) = *(const float4*)(&Bs[k][tx*8+4]);
      #pragma unroll
      for (int i=0;i<8;i++)
        #pragma unroll
        for (int j=0;j<8;j++) acc[i][j] = fmaf(a8[i], b8[j], acc[i][j]);
    }
    __syncthreads();
  }

  float bj[8];
  if (EPI==1 || EPI==3){
    #pragma unroll
    for (int j=0;j<8;j++) bj[j] = bias[col0 + tx*8 + j];
  }
  #pragma unroll
  for (int i=0;i<8;i++){
    int row = row0 + ty*8 + i;
    float* crow = C + (size_t)row*N + col0 + tx*8;
    if (EPI==0){
      *(float4*)(crow)   = make_float4(acc[i][0],acc[i][1],acc[i][2],acc[i][3]);
      *(float4*)(crow+4) = make_float4(acc[i][4],acc[i][5],acc[i][6],acc[i][7]);
    } else if (EPI==1){
      float o[8];
      #pragma unroll
      for (int j=0;j<8;j++) o[j] = gelu_tanh(acc[i][j] + bj[j]);
      *(float4*)(crow)   = make_float4(o[0],o[1],o[2],o[3]);
      *(float4*)(crow+4) = make_float4(o[4],o[5],o[6],o[7]);
    } else if (EPI==2){
      float4 c0 = *(float4*)(crow), c1 = *(float4*)(crow+4);
      c0.x+=acc[i][0]; c0.y+=acc[i][1]; c0.z+=acc[i][2]; c0.w+=acc[i][3];
      c1.x+=acc[i][4]; c1.y+=acc[i][5]; c1.z+=acc[i][6]; c1.w+=acc[i][7];
      *(float4*)(crow)=c0; *(float4*)(crow+4)=c1;
    } else {
      float s = rowscale[(size_t)row * E_];
      float4 c0 = *(float4*)(crow), c1 = *(float4*)(crow+4);
      c0.x += s*(acc[i][0]+bj[0]); c0.y += s*(acc[i][1]+bj[1]);
      c0.z += s*(acc[i][2]+bj[2]); c0.w += s*(acc[i][3]+bj[3]);
      c1.x += s*(acc[i][4]+bj[4]); c1.y += s*(acc[i][5]+bj[5]);
      c1.z += s*(acc[i][6]+bj[6]); c1.w += s*(acc[i][7]+bj[7]);
      *(float4*)(crow)=c0; *(float4*)(crow+4)=c1;
    }
  }
}

// ---------------- causal depthwise conv (KC=4) + bias ----------------
__global__ __launch_bounds__(256) void k_conv(const float* __restrict__ xz,
    const float* __restrict__ cw, const float* __restrict__ cb, float* __restrict__ xi){
  int t = blockIdx.x;
  int b = t >> 10, s = t & (S_-1);
  int c0 = threadIdx.x << 2;
  float4 acc = *(const float4*)(cb + c0);
  #pragma unroll
  for (int k=0;k<KC_;k++){
    int ss = s - (KC_-1) + k;
    if (ss >= 0){
      float4 xv = *(const float4*)(xz + ((size_t)(b*S_+ss))*(2*DI_) + c0);
      acc.x += xv.x * cw[(c0+0)*KC_ + k];
      acc.y += xv.y * cw[(c0+1)*KC_ + k];
      acc.z += xv.z * cw[(c0+2)*KC_ + k];
      acc.w += xv.w * cw[(c0+3)*KC_ + k];
    }
  }
  *(float4*)(xi + (size_t)t*DI_ + c0) = acc;
}

// ------- per-token: B_param (x_proj rows 16..31), delta=softplus(dt), sdb -------
__global__ __launch_bounds__(256) void k_xdbl(const float* __restrict__ xi,
    const float* __restrict__ xpw, const float* __restrict__ dtw,
    const float* __restrict__ dtb, float* __restrict__ delta, float* __restrict__ sdb){
  int t = blockIdx.x;
  __shared__ float xrow[DI_];
  __shared__ float outv[32];
  int tid = threadIdx.x;
  *(float4*)(xrow + (tid<<2)) = *(const float4*)(xi + (size_t)t*DI_ + (tid<<2));
  __syncthreads();
  int wid = tid >> 6, lane = tid & 63;
  #pragma unroll
  for (int oi=0; oi<8; ++oi){
    int o = wid*8 + oi;
    const float* wr = (o < 16) ? (xpw + (size_t)(DS_ + o)*DI_) : (dtw + (size_t)(o-16)*DI_);
    float sum = 0.f;
    #pragma unroll
    for (int j=0;j<16;j++) sum += xrow[lane + 64*j] * wr[lane + 64*j];
    #pragma unroll
    for (int off=32; off>=1; off>>=1) sum += __shfl_down(sum, off);
    if (lane == 0) outv[o] = sum;
  }
  __syncthreads();
  if (tid < DS_){
    float d  = outv[16+tid] + dtb[tid];
    float sp = fmaxf(d, 0.f) + log1pf(expf(-fabsf(d)));   // softplus, stable
    delta[(size_t)t*DS_ + tid] = sp;
    float pr = sp * outv[tid];                            // * B_param
    #pragma unroll
    for (int off=8; off>=1; off>>=1) pr += __shfl_down(pr, off);
    if (tid == 0) sdb[t] = pr;
  }
}

// ---------------- negA = -exp(A_log) ----------------
__global__ __launch_bounds__(256) void k_negA(const float* __restrict__ Alog, float* __restrict__ negA){
  int i = blockIdx.x*256 + threadIdx.x;
  negA[i] = -expf(Alog[i]);
}

// ---------------- a, b tensors ----------------
__global__ __launch_bounds__(256) void k_ab(const float* __restrict__ delta,
    const float* __restrict__ sdb, const float* __restrict__ negA,
    const float* __restrict__ xi, float* __restrict__ a, float* __restrict__ bb){
  int t = blockIdx.x;
  __shared__ float dl[DS_];
  if (threadIdx.x < DS_) dl[threadIdx.x] = delta[(size_t)t*DS_ + threadIdx.x];
  __syncthreads();
  float s = sdb[t];
  int di0 = threadIdx.x << 2;
  float4 xv = *(const float4*)(xi + (size_t)t*DI_ + di0);
  float av[4];
  #pragma unroll
  for (int i=0;i<4;i++){
    const float* nA = negA + (size_t)(di0+i)*DS_;
    float sum = 0.f;
    #pragma unroll
    for (int ds=0; ds<DS_; ds++) sum += expf(dl[ds] * nA[ds]);
    av[i] = sum;
  }
  *(float4*)(a + (size_t)t*DI_ + di0) = make_float4(av[0],av[1],av[2],av[3]);
  float4 bv; bv.x=xv.x*s; bv.y=xv.y*s; bv.z=xv.z*s; bv.w=xv.w*s;
  *(float4*)(bb + (size_t)t*DI_ + di0) = bv;
}

// ---------------- chunked scan, phase 1: per-chunk (aprod, yend) ----------------
__global__ __launch_bounds__(256) void k_scan1(const float* __restrict__ a,
    const float* __restrict__ bb, float* __restrict__ aprod, float* __restrict__ yend){
  int g  = blockIdx.x*256 + threadIdx.x;        // (b, chunk, di)
  int di = g & (DI_-1);
  int c  = (g >> 10) & (NCHUNK-1);
  int b  = g >> 14;
  float ap = 1.f, y = 0.f;
  size_t base = ((size_t)b*S_ + (size_t)c*CHL)*DI_ + di;
  #pragma unroll 4
  for (int i=0;i<CHL;i++){
    float at = a[base + (size_t)i*DI_], bt = bb[base + (size_t)i*DI_];
    y = at*y + bt; ap *= at;
  }
  aprod[g] = ap; yend[g] = y;
}

// -------- phase 2: carry + final scan, fused with y*silu(z) -> yact --------
__global__ __launch_bounds__(256) void k_scan2(const float* __restrict__ a,
    const float* __restrict__ bb, const float* __restrict__ xz,
    const float* __restrict__ aprod, const float* __restrict__ yend,
    float* __restrict__ yact){
  int g  = blockIdx.x*256 + threadIdx.x;
  int di = g & (DI_-1);
  int c  = (g >> 10) & (NCHUNK-1);
  int b  = g >> 14;
  float y = 0.f;
  for (int j=0;j<c;j++){
    int gg = ((b*NCHUNK + j) << 10) + di;
    y = aprod[gg]*y + yend[gg];
  }
  size_t base = ((size_t)b*S_ + (size_t)c*CHL)*DI_ + di;
  #pragma unroll 4
  for (int i=0;i<CHL;i++){
    float at = a[base + (size_t)i*DI_], bt = bb[base + (size_t)i*DI_];
    y = at*y + bt;
    float z = xz[((size_t)(b*S_ + c*CHL + i))*(2*DI_) + DI_ + di];
    float sil = z / (1.f + expf(-z));
    yact[base + (size_t)i*DI_] = y * sil;
  }
}

// ---------------- router: probs, top-2 weights (dense map), indices ----------------
__global__ __launch_bounds__(64) void k_router(const float* __restrict__ xn,
    const float* __restrict__ rw, const float* __restrict__ rb,
    float* __restrict__ probs, float* __restrict__ wfull, int* __restrict__ topi){
  int t = blockIdx.x, lane = threadIdx.x;
  float xv[8];
  #pragma unroll
  for (int j=0;j<8;j++) xv[j] = xn[(size_t)t*D_ + lane + 64*j];
  __shared__ float lg[E_];
  #pragma unroll
  for (int e=0;e<E_;e++){
    float s = 0.f;
    #pragma unroll
    for (int j=0;j<8;j++) s += xv[j]*rw[(size_t)e*D_ + lane + 64*j];
    #pragma unroll
    for (int off=32; off>=1; off>>=1) s += __shfl_down(s, off);
    if (lane==0) lg[e] = s + rb[e];
  }
  __syncthreads();
  if (lane==0){
    float mx = lg[0];
    #pragma unroll
    for (int e=1;e<E_;e++) mx = fmaxf(mx, lg[e]);
    float pe[E_]; float sum = 0.f;
    #pragma unroll
    for (int e=0;e<E_;e++){ pe[e] = expf(lg[e]-mx); sum += pe[e]; }
    #pragma unroll
    for (int e=0;e<E_;e++){ pe[e] /= sum; probs[(size_t)t*E_ + e] = pe[e]; }
    int i1 = 0;
    #pragma unroll
    for (int e=1;e<E_;e++) if (pe[e] > pe[i1]) i1 = e;
    int i2 = (i1==0) ? 1 : 0;
    #pragma unroll
    for (int e=0;e<E_;e++) if (e!=i1 && pe[e] > pe[i2]) i2 = e;
    float wsum = pe[i1] + pe[i2];
    #pragma unroll
    for (int e=0;e<E_;e++) wfull[(size_t)t*E_ + e] = 0.f;
    wfull[(size_t)t*E_ + i1] = pe[i1]/wsum;
    wfull[(size_t)t*E_ + i2] = pe[i2]/wsum;
    topi[t*2] = i1; topi[t*2+1] = i2;
  }
}

// ---------------- aux loss (deterministic single-block reduce) ----------------
__global__ __launch_bounds__(256) void k_aux(const float* __restrict__ probs,
    const int* __restrict__ topi, float* __restrict__ dst, int first){
  float ps[E_]; int cnt[E_];
  #pragma unroll
  for (int e=0;e<E_;e++){ ps[e]=0.f; cnt[e]=0; }
  for (int t=threadIdx.x; t<NTOK; t+=256){
    #pragma unroll
    for (int e=0;e<E_;e++) ps[e] += probs[(size_t)t*E_ + e];
    int a_ = topi[t*2], b_ = topi[t*2+1];
    #pragma unroll
    for (int e=0;e<E_;e++) cnt[e] += (a_==e) + (b_==e);
  }
  int lane = threadIdx.x & 63, wid = threadIdx.x >> 6;
  __shared__ float rps[4][E_];
  __shared__ int   rcnt[4][E_];
  #pragma unroll
  for (int e=0;e<E_;e++){
    float v = ps[e]; int cc = cnt[e];
    #pragma unroll
    for (int off=32; off>=1; off>>=1){ v += __shfl_down(v, off); cc += __shfl_down(cc, off); }
    if (lane==0){ rps[wid][e]=v; rcnt[wid][e]=cc; }
  }
  __syncthreads();
  if (threadIdx.x==0){
    float aux = 0.f;
    #pragma unroll
    for (int e=0;e<E_;e++){
      float P = (rps[0][e]+rps[1][e]+rps[2][e]+rps[3][e]) * (1.0f/NTOK);
      float f = (float)(rcnt[0][e]+rcnt[1][e]+rcnt[2][e]+rcnt[3][e]) * (1.0f/(NTOK*2.0f));
      aux += f*P;
    }
    aux *= (float)E_;
    if (first) dst[0] = aux; else dst[0] += aux;
  }
}

// ---------------- host ----------------
extern "C" void kernel_launch(void* const* d_in, const int* in_sizes, int n_in,
                              void* d_out, int out_size, void* d_ws, size_t ws_size,
                              hipStream_t stream) {
  const int*   input_ids  = (const int*)  d_in[0];
  const float* tok_emb    = (const float*)d_in[1];
  const float* pos_emb    = (const float*)d_in[2];
  const float* norm1_w    = (const float*)d_in[3];
  const float* norm2_w    = (const float*)d_in[4];
  const float* in_proj_w  = (const float*)d_in[5];
  const float* conv_w     = (const float*)d_in[6];
  const float* conv_b     = (const float*)d_in[7];
  const float* x_proj_w   = (const float*)d_in[8];
  const float* dt_proj_w  = (const float*)d_in[9];
  const float* dt_proj_b  = (const float*)d_in[10];
  const float* A_log      = (const float*)d_in[11];
  const float* out_proj_w = (const float*)d_in[13];
  const float* router_w   = (const float*)d_in[14];
  const float* router_b   = (const float*)d_in[15];
  const float* w1         = (const float*)d_in[16];
  const float* b1         = (const float*)d_in[17];
  const float* w2         = (const float*)d_in[18];
  const float* b2         = (const float*)d_in[19];
  const float* final_norm = (const float*)d_in[20];
  const float* lm_head_w  = (const float*)d_in[21];
  float* out = (float*)d_out;

  float* ws = (float*)d_ws;
  float* x     = ws;                      // 2048*512
  float* xn    = x     + (size_t)NTOK*D_;       // 2048*512
  float* xz    = xn    + (size_t)NTOK*D_;       // 2048*2048
  float* xi    = xz    + (size_t)NTOK*2*DI_;    // 2048*1024
  float* a     = xi    + (size_t)NTOK*DI_;      // 2048*1024
  float* bb    = a     + (size_t)NTOK*DI_;      // 2048*1024
  float* yact  = bb    + (size_t)NTOK*DI_;      // 2048*1024
  float* h     = a;    // alias over a+bb (16MB), free after scan
  float* delta = yact  + (size_t)NTOK*DI_;      // 2048*16
  float* sdb   = delta + (size_t)NTOK*DS_;      // 2048
  float* negA  = sdb   + NTOK;                  // 1024*16
  float* aprod = negA  + (size_t)DI_*DS_;       // 32768
  float* yendb = aprod + NTOK*NCHUNK;           // 32768
  float* probs = yendb + NTOK*NCHUNK;           // 2048*8
  float* wfull = probs + (size_t)NTOK*E_;       // 2048*8
  int*   topi  = (int*)(wfull + (size_t)NTOK*E_); // 2048*2

  float* aux_dst = out + (size_t)NTOK*VOCAB;

  k_embed<<<NTOK, 128, 0, stream>>>(input_ids, tok_emb, pos_emb, x);

  for (int l=0; l<2; ++l){
    // ---- mamba ----
    k_rmsnorm<<<NTOK, 128, 0, stream>>>(x, norm1_w + (size_t)l*D_, xn);
    gemm_f32<0><<<dim3(16,16), 256, 0, stream>>>(xn, in_proj_w + (size_t)l*2*DI_*D_,
                                                 xz, nullptr, nullptr, NTOK, 2*DI_, D_);
    k_conv<<<NTOK, 256, 0, stream>>>(xz, conv_w + (size_t)l*DI_*KC_, conv_b + (size_t)l*DI_, xi);
    k_xdbl<<<NTOK, 256, 0, stream>>>(xi, x_proj_w + (size_t)l*2*DS_*DI_,
                                     dt_proj_w + (size_t)l*DS_*DI_, dt_proj_b + (size_t)l*DS_,
                                     delta, sdb);
    k_negA<<<(DI_*DS_)/256, 256, 0, stream>>>(A_log + (size_t)l*DI_*DS_, negA);
    k_ab<<<NTOK, 256, 0, stream>>>(delta, sdb, negA, xi, a, bb);
    k_scan1<<<(NTOK*NCHUNK)/256, 256, 0, stream>>>(a, bb, aprod, yendb);
    k_scan2<<<(NTOK*NCHUNK)/256, 256, 0, stream>>>(a, bb, xz, aprod, yendb, yact);
    gemm_f32<2><<<dim3(16,4), 256, 0, stream>>>(yact, out_proj_w + (size_t)l*D_*DI_,
                                                x, nullptr, nullptr, NTOK, D_, DI_);
    // ---- moe ----
    k_rmsnorm<<<NTOK, 128, 0, stream>>>(x, norm2_w + (size_t)l*D_, xn);
    k_router<<<NTOK, 64, 0, stream>>>(xn, router_w + (size_t)l*E_*D_, router_b + (size_t)l*E_,
                                      probs, wfull, topi);
    k_aux<<<1, 256, 0, stream>>>(probs, topi, aux_dst, l==0 ? 1 : 0);
    for (int e=0; e<E_; ++e){
      size_t we = (size_t)(l*E_ + e);
      gemm_f32<1><<<dim3(16,16), 256, 0, stream>>>(xn, w1 + we*DFF_*D_, h,
                                                   b1 + we*DFF_, nullptr, NTOK, DFF_, D_);
      gemm_f32<3><<<dim3(16,4), 256, 0, stream>>>(h, w2 + we*D_*DFF_, x,
                                                  b2 + we*D_, wfull + e, NTOK, D_, DFF_);
    }
  }

  // ---- head ----
  k_rmsnorm<<<NTOK, 128, 0, stream>>>(x, final_norm, xn);
  gemm_f32<0><<<dim3(16,250), 256, 0, stream>>>(xn, lm_head_w, out, nullptr, nullptr,
                                                NTOK, VOCAB, D_);
}

// Round 2
// 1363.548 us; speedup vs baseline: 4.8604x; 4.8604x over previous
//
#include <hip/hip_runtime.h>
#include <math.h>

#define S_    1024
#define D_    512
#define DI_   1024
#define DS_   16
#define KC_   4
#define E_    8
#define DFF_  2048
#define NTOK  2048     // B*S
#define VOCAB 32000
#define NCHUNK 16
#define CHL    64      // S_/NCHUNK

typedef unsigned short ushort;
typedef unsigned int   uint;
typedef __attribute__((ext_vector_type(8))) short short8;
typedef __attribute__((ext_vector_type(4))) float f32x4;

// ---------------- helpers ----------------
__device__ __forceinline__ float gelu_tanh(float x){
  float x3 = x*x*x;
  return 0.5f*x*(1.0f + tanhf(0.7978845608028654f*(x + 0.044715f*x3)));
}

// round-half-up fp32 -> bf16 (bias only on exact ties: negligible for data)
__device__ __forceinline__ ushort f2bf_rnd(float f){
  uint u = __float_as_uint(f);
  return (ushort)((u + 0x8000u) >> 16);
}
__device__ __forceinline__ float bf2f(ushort h){
  return __uint_as_float(((uint)h) << 16);
}
// split f = hi + lo (+ ~2^-17 residual)
__device__ __forceinline__ void split1(float f, ushort& h, ushort& l){
  h = f2bf_rnd(f);
  float fh = bf2f(h);
  l = (ushort)(__float_as_uint(f - fh) >> 16);   // truncate lo
}

// ---------------- embed: x = tok_emb[ids] + pos_emb ----------------
__global__ __launch_bounds__(128) void k_embed(const int* __restrict__ ids,
    const float* __restrict__ tok, const float* __restrict__ pos, float* __restrict__ x){
  int t  = blockIdx.x;
  int d4 = threadIdx.x << 2;
  int s  = t & (S_-1);
  int id = ids[t];
  float4 tv = *(const float4*)(tok + (size_t)id*D_ + d4);
  float4 pv = *(const float4*)(pos + (size_t)s*D_ + d4);
  float4 o; o.x=tv.x+pv.x; o.y=tv.y+pv.y; o.z=tv.z+pv.z; o.w=tv.w+pv.w;
  *(float4*)(x + (size_t)t*D_ + d4) = o;
}

// ---------------- rmsnorm ----------------
__global__ __launch_bounds__(128) void k_rmsnorm(const float* __restrict__ x,
    const float* __restrict__ w, float* __restrict__ out){
  int t = blockIdx.x;
  int d4 = threadIdx.x << 2;
  float4 v = *(const float4*)(x + (size_t)t*D_ + d4);
  float ss = v.x*v.x + v.y*v.y + v.z*v.z + v.w*v.w;
  #pragma unroll
  for (int off=32; off>=1; off>>=1) ss += __shfl_down(ss, off);
  __shared__ float sred[2];
  if ((threadIdx.x & 63) == 0) sred[threadIdx.x >> 6] = ss;
  __syncthreads();
  float total = sred[0] + sred[1];
  float scale = 1.0f / sqrtf(total * (1.0f/D_) + 1e-6f);
  float4 wv = *(const float4*)(w + d4);
  float4 o; o.x=v.x*scale*wv.x; o.y=v.y*scale*wv.y; o.z=v.z*scale*wv.z; o.w=v.w*scale*wv.w;
  *(float4*)(out + (size_t)t*D_ + d4) = o;
}

// ---------------- fp32 GEMM (kept for in_proj / out_proj) ----------------
// EPI 0: C = acc   EPI 2: C += acc
template<int EPI>
__global__ __launch_bounds__(256) void gemm_f32(
    const float* __restrict__ A, const float* __restrict__ W,
    float* __restrict__ C, int M, int N, int K)
{
  __shared__ float As[16][128];
  __shared__ float Bs[16][128];
  const int tid  = threadIdx.x;
  const int row0 = blockIdx.x * 128;
  const int col0 = blockIdx.y * 128;
  const int tx = tid & 15, ty = tid >> 4;
  float acc[8][8];
  #pragma unroll
  for (int i=0;i<8;i++)
    #pragma unroll
    for (int j=0;j<8;j++) acc[i][j]=0.f;

  for (int kk=0; kk<K; kk+=16){
    #pragma unroll
    for (int it=0; it<2; ++it){
      int ci = tid + it*256;
      int r = ci >> 2, c4 = (ci & 3) << 2;
      float4 av = *(const float4*)(A + (size_t)(row0+r)*K + kk + c4);
      float4 wv = *(const float4*)(W + (size_t)(col0+r)*K + kk + c4);
      As[c4+0][r]=av.x; As[c4+1][r]=av.y; As[c4+2][r]=av.z; As[c4+3][r]=av.w;
      Bs[c4+0][r]=wv.x; Bs[c4+1][r]=wv.y; Bs[c4+2][r]=wv.z; Bs[c4+3][r]=wv.w;
    }
    __syncthreads();
    #pragma unroll
    for (int k=0;k<16;k++){
      float a8[8], b8[8];
      *(float4*)(a8)   = *(const float4*)(&As[k][ty*8]);
      *(float4*)(a8+4) = *(const float4*)(&As[k][ty*8+4]);
      *(float4*)(b8)   = *(const float4*)(&Bs[k][tx*8]);
      *(float4*)(b8+4) = *(const float4*)(&Bs[k][tx*8+4]);
      #pragma unroll
      for (int i=0;i<8;i++)
        #pragma unroll
        for (int j=0;j<8;j++) acc[i][j] = fmaf(a8[i], b8[j], acc[i][j]);
    }
    __syncthreads();
  }
  #pragma unroll
  for (int i=0;i<8;i++){
    int row = row0 + ty*8 + i;
    float* crow = C + (size_t)row*N + col0 + tx*8;
    if (EPI==0){
      *(float4*)(crow)   = make_float4(acc[i][0],acc[i][1],acc[i][2],acc[i][3]);
      *(float4*)(crow+4) = make_float4(acc[i][4],acc[i][5],acc[i][6],acc[i][7]);
    } else {
      float4 c0 = *(float4*)(crow), c1 = *(float4*)(crow+4);
      c0.x+=acc[i][0]; c0.y+=acc[i][1]; c0.z+=acc[i][2]; c0.w+=acc[i][3];
      c1.x+=acc[i][4]; c1.y+=acc[i][5]; c1.z+=acc[i][6]; c1.w+=acc[i][7];
      *(float4*)(crow)=c0; *(float4*)(crow+4)=c1;
    }
  }
}

// ============ split-bf16 MFMA GEMM: C[M,N] = A[M,K] @ W[N,K]^T ============
// NT=3: hi*hi + hi*lo + lo*hi    NT=4: + lo*lo
// EPI 0: dense, C[row*N+col] = v                        (lm_head)
// EPI 1: sparse, A row via gidx; C=h[slot], gelu(v+b)   (MoE w1)
// EPI 2: sparse, A row = h[slot]; C=eo[slot]=sw*(v+b)   (MoE w2)
template<int EPI, int NT>
__global__ __launch_bounds__(256, 2) void gemm_mfma(
    const float* __restrict__ A, const float* __restrict__ Wb,
    float* __restrict__ Cb, const float* __restrict__ biasb,
    const float* __restrict__ slotw, const int* __restrict__ gidx,
    const int* __restrict__ offs, int M, int N, int K)
{
  int off = 0, cnt = M;
  if (EPI==1 || EPI==2){
    off = offs[blockIdx.z];
    cnt = offs[blockIdx.z+1] - off;
    if ((int)(blockIdx.x*128) >= cnt) return;
  }
  const float* W    = Wb + (size_t)blockIdx.z * N * K;
  const float* bias = (EPI==1||EPI==2) ? (biasb + (size_t)blockIdx.z * N) : biasb;

  __shared__ ushort As_h[128][40];
  __shared__ ushort As_l[128][40];
  __shared__ ushort Ws_h[128][40];
  __shared__ ushort Ws_l[128][40];

  const int tid  = threadIdx.x;
  const int row0 = blockIdx.x * 128;
  const int col0 = blockIdx.y * 128;

  // staging assignment: thread covers tile row sr, 16 consecutive k at sh
  const int sr = tid >> 1;
  const int sh = (tid & 1) * 16;

  const float* arow;
  if (EPI==1){
    int lrr = row0 + sr; if (lrr > cnt-1) lrr = cnt-1;
    arow = A + (size_t)gidx[off + lrr] * K;
  } else if (EPI==2){
    int lrr = row0 + sr; if (lrr > cnt-1) lrr = cnt-1;
    arow = A + (size_t)(off + lrr) * K;
  } else {
    arow = A + (size_t)(row0 + sr) * K;
  }
  const float* wrow = W + (size_t)(col0 + sr) * K;

  const int lane = tid & 63;
  const int wid  = tid >> 6;
  const int wrM  = (wid >> 1) * 64;
  const int wcN  = (wid & 1) * 64;
  const int lr   = lane & 15;
  const int ks   = lane >> 4;

  f32x4 zero = {0.f, 0.f, 0.f, 0.f};
  f32x4 acc[4][4];
  #pragma unroll
  for (int i=0;i<4;i++)
    #pragma unroll
    for (int j=0;j<4;j++) acc[i][j] = zero;

  float4 ra[4], rw[4];
  #pragma unroll
  for (int q=0;q<4;q++){
    ra[q] = *(const float4*)(arow + sh + q*4);
    rw[q] = *(const float4*)(wrow + sh + q*4);
  }

  for (int kk=0; kk<K; kk+=32){
    // convert current staged regs to hi/lo
    short8 cah[2], cal[2], cwh[2], cwl[2];
    #pragma unroll
    for (int hf=0; hf<2; ++hf){
      short8 h1, l1, h2, l2;
      #pragma unroll
      for (int q=0;q<2;q++){
        float fa[4] = {ra[hf*2+q].x, ra[hf*2+q].y, ra[hf*2+q].z, ra[hf*2+q].w};
        float fw[4] = {rw[hf*2+q].x, rw[hf*2+q].y, rw[hf*2+q].z, rw[hf*2+q].w};
        #pragma unroll
        for (int m=0;m<4;m++){
          ushort hh, ll;
          split1(fa[m], hh, ll); h1[q*4+m]=(short)hh; l1[q*4+m]=(short)ll;
          split1(fw[m], hh, ll); h2[q*4+m]=(short)hh; l2[q*4+m]=(short)ll;
        }
      }
      cah[hf]=h1; cal[hf]=l1; cwh[hf]=h2; cwl[hf]=l2;
    }
    __syncthreads();   // prev MFMA phase done reading LDS
    *(short8*)&As_h[sr][sh]   = cah[0];  *(short8*)&As_h[sr][sh+8] = cah[1];
    *(short8*)&As_l[sr][sh]   = cal[0];  *(short8*)&As_l[sr][sh+8] = cal[1];
    *(short8*)&Ws_h[sr][sh]   = cwh[0];  *(short8*)&Ws_h[sr][sh+8] = cwh[1];
    *(short8*)&Ws_l[sr][sh]   = cwl[0];  *(short8*)&Ws_l[sr][sh+8] = cwl[1];
    if (kk + 32 < K){
      #pragma unroll
      for (int q=0;q<4;q++){
        ra[q] = *(const float4*)(arow + kk + 32 + sh + q*4);
        rw[q] = *(const float4*)(wrow + kk + 32 + sh + q*4);
      }
    }
    __syncthreads();

    short8 ah[4], al[4], bh[4], bl[4];
    #pragma unroll
    for (int f=0; f<4; ++f){
      int rA = wrM + f*16 + lr;
      ah[f] = *(const short8*)&As_h[rA][ks*8];
      al[f] = *(const short8*)&As_l[rA][ks*8];
      int rB = wcN + f*16 + lr;
      bh[f] = *(const short8*)&Ws_h[rB][ks*8];
      bl[f] = *(const short8*)&Ws_l[rB][ks*8];
    }
    #pragma unroll
    for (int i=0;i<4;i++)
      #pragma unroll
      for (int j=0;j<4;j++){
        f32x4 c = acc[i][j];
        if (NT==4) c = __builtin_amdgcn_mfma_f32_16x16x32_bf16(al[i], bl[j], c, 0,0,0);
        c = __builtin_amdgcn_mfma_f32_16x16x32_bf16(al[i], bh[j], c, 0,0,0);
        c = __builtin_amdgcn_mfma_f32_16x16x32_bf16(ah[i], bl[j], c, 0,0,0);
        c = __builtin_amdgcn_mfma_f32_16x16x32_bf16(ah[i], bh[j], c, 0,0,0);
        acc[i][j] = c;
      }
  }

  float bj[4];
  if (EPI==1 || EPI==2){
    #pragma unroll
    for (int j=0;j<4;j++) bj[j] = bias[col0 + wcN + j*16 + lr];
  }
  #pragma unroll
  for (int i=0;i<4;i++){
    #pragma unroll
    for (int jj=0;jj<4;jj++){
      int rt   = wrM + i*16 + ks*4 + jj;   // row within tile
      int grow = row0 + rt;
      if (EPI==0){
        float* cr = Cb + (size_t)grow*N + col0 + wcN + lr;
        #pragma unroll
        for (int j=0;j<4;j++) cr[j*16] = acc[i][j][jj];
      } else if (EPI==1){
        if (grow < cnt){
          int slot = off + grow;
          float* cr = Cb + (size_t)slot*N + col0 + wcN + lr;
          #pragma unroll
          for (int j=0;j<4;j++) cr[j*16] = gelu_tanh(acc[i][j][jj] + bj[j]);
        }
      } else {
        if (grow < cnt){
          int slot = off + grow;
          float sw = slotw[slot];
          float* cr = Cb + (size_t)slot*N + col0 + wcN + lr;
          #pragma unroll
          for (int j=0;j<4;j++) cr[j*16] = sw*(acc[i][j][jj] + bj[j]);
        }
      }
    }
  }
}

// ---------------- causal depthwise conv (KC=4) + bias ----------------
__global__ __launch_bounds__(256) void k_conv(const float* __restrict__ xz,
    const float* __restrict__ cw, const float* __restrict__ cb, float* __restrict__ xi){
  int t = blockIdx.x;
  int b = t >> 10, s = t & (S_-1);
  int c0 = threadIdx.x << 2;
  float4 acc = *(const float4*)(cb + c0);
  #pragma unroll
  for (int k=0;k<KC_;k++){
    int ss = s - (KC_-1) + k;
    if (ss >= 0){
      float4 xv = *(const float4*)(xz + ((size_t)(b*S_+ss))*(2*DI_) + c0);
      acc.x += xv.x * cw[(c0+0)*KC_ + k];
      acc.y += xv.y * cw[(c0+1)*KC_ + k];
      acc.z += xv.z * cw[(c0+2)*KC_ + k];
      acc.w += xv.w * cw[(c0+3)*KC_ + k];
    }
  }
  *(float4*)(xi + (size_t)t*DI_ + c0) = acc;
}

// ------- per-token: B_param, delta=softplus(dt), sdb = sum(delta*B) -------
__global__ __launch_bounds__(256) void k_xdbl(const float* __restrict__ xi,
    const float* __restrict__ xpw, const float* __restrict__ dtw,
    const float* __restrict__ dtb, float* __restrict__ delta, float* __restrict__ sdb){
  int t = blockIdx.x;
  __shared__ float xrow[DI_];
  __shared__ float outv[32];
  int tid = threadIdx.x;
  *(float4*)(xrow + (tid<<2)) = *(const float4*)(xi + (size_t)t*DI_ + (tid<<2));
  __syncthreads();
  int wid = tid >> 6, lane = tid & 63;
  #pragma unroll
  for (int oi=0; oi<8; ++oi){
    int o = wid*8 + oi;
    const float* wr = (o < 16) ? (xpw + (size_t)(DS_ + o)*DI_) : (dtw + (size_t)(o-16)*DI_);
    float sum = 0.f;
    #pragma unroll
    for (int j=0;j<16;j++) sum += xrow[lane + 64*j] * wr[lane + 64*j];
    #pragma unroll
    for (int off=32; off>=1; off>>=1) sum += __shfl_down(sum, off);
    if (lane == 0) outv[o] = sum;
  }
  __syncthreads();
  if (tid < DS_){
    float d  = outv[16+tid] + dtb[tid];
    float sp = fmaxf(d, 0.f) + log1pf(expf(-fabsf(d)));
    delta[(size_t)t*DS_ + tid] = sp;
    float pr = sp * outv[tid];
    #pragma unroll
    for (int off=8; off>=1; off>>=1) pr += __shfl_down(pr, off);
    if (tid == 0) sdb[t] = pr;
  }
}

__global__ __launch_bounds__(256) void k_negA(const float* __restrict__ Alog, float* __restrict__ negA){
  int i = blockIdx.x*256 + threadIdx.x;
  negA[i] = -expf(Alog[i]);
}

__global__ __launch_bounds__(256) void k_ab(const float* __restrict__ delta,
    const float* __restrict__ sdb, const float* __restrict__ negA,
    const float* __restrict__ xi, float* __restrict__ a, float* __restrict__ bb){
  int t = blockIdx.x;
  __shared__ float dl[DS_];
  if (threadIdx.x < DS_) dl[threadIdx.x] = delta[(size_t)t*DS_ + threadIdx.x];
  __syncthreads();
  float s = sdb[t];
  int di0 = threadIdx.x << 2;
  float4 xv = *(const float4*)(xi + (size_t)t*DI_ + di0);
  float av[4];
  #pragma unroll
  for (int i=0;i<4;i++){
    const float* nA = negA + (size_t)(di0+i)*DS_;
    float sum = 0.f;
    #pragma unroll
    for (int ds=0; ds<DS_; ds++) sum += expf(dl[ds] * nA[ds]);
    av[i] = sum;
  }
  *(float4*)(a + (size_t)t*DI_ + di0) = make_float4(av[0],av[1],av[2],av[3]);
  float4 bv; bv.x=xv.x*s; bv.y=xv.y*s; bv.z=xv.z*s; bv.w=xv.w*s;
  *(float4*)(bb + (size_t)t*DI_ + di0) = bv;
}

__global__ __launch_bounds__(256) void k_scan1(const float* __restrict__ a,
    const float* __restrict__ bb, float* __restrict__ aprod, float* __restrict__ yend){
  int g  = blockIdx.x*256 + threadIdx.x;
  int di = g & (DI_-1);
  int c  = (g >> 10) & (NCHUNK-1);
  int b  = g >> 14;
  float ap = 1.f, y = 0.f;
  size_t base = ((size_t)b*S_ + (size_t)c*CHL)*DI_ + di;
  #pragma unroll 4
  for (int i=0;i<CHL;i++){
    float at = a[base + (size_t)i*DI_], bt = bb[base + (size_t)i*DI_];
    y = at*y + bt; ap *= at;
  }
  aprod[g] = ap; yend[g] = y;
}

__global__ __launch_bounds__(256) void k_scan2(const float* __restrict__ a,
    const float* __restrict__ bb, const float* __restrict__ xz,
    const float* __restrict__ aprod, const float* __restrict__ yend,
    float* __restrict__ yact){
  int g  = blockIdx.x*256 + threadIdx.x;
  int di = g & (DI_-1);
  int c  = (g >> 10) & (NCHUNK-1);
  int b  = g >> 14;
  float y = 0.f;
  for (int j=0;j<c;j++){
    int gg = ((b*NCHUNK + j) << 10) + di;
    y = aprod[gg]*y + yend[gg];
  }
  size_t base = ((size_t)b*S_ + (size_t)c*CHL)*DI_ + di;
  #pragma unroll 4
  for (int i=0;i<CHL;i++){
    float at = a[base + (size_t)i*DI_], bt = bb[base + (size_t)i*DI_];
    y = at*y + bt;
    float z = xz[((size_t)(b*S_ + c*CHL + i))*(2*DI_) + DI_ + di];
    float sil = z / (1.f + expf(-z));
    yact[base + (size_t)i*DI_] = y * sil;
  }
}

// ------- router: probs, top-2 indices + normalized weights -------
__global__ __launch_bounds__(64) void k_router(const float* __restrict__ xn,
    const float* __restrict__ rw, const float* __restrict__ rb,
    float* __restrict__ probs, float* __restrict__ topw, int* __restrict__ topi){
  int t = blockIdx.x, lane = threadIdx.x;
  float xv[8];
  #pragma unroll
  for (int j=0;j<8;j++) xv[j] = xn[(size_t)t*D_ + lane + 64*j];
  __shared__ float lg[E_];
  #pragma unroll
  for (int e=0;e<E_;e++){
    float s = 0.f;
    #pragma unroll
    for (int j=0;j<8;j++) s += xv[j]*rw[(size_t)e*D_ + lane + 64*j];
    #pragma unroll
    for (int off=32; off>=1; off>>=1) s += __shfl_down(s, off);
    if (lane==0) lg[e] = s + rb[e];
  }
  __syncthreads();
  if (lane==0){
    float mx = lg[0];
    #pragma unroll
    for (int e=1;e<E_;e++) mx = fmaxf(mx, lg[e]);
    float pe[E_]; float sum = 0.f;
    #pragma unroll
    for (int e=0;e<E_;e++){ pe[e] = expf(lg[e]-mx); sum += pe[e]; }
    #pragma unroll
    for (int e=0;e<E_;e++){ pe[e] /= sum; probs[(size_t)t*E_ + e] = pe[e]; }
    int i1 = 0;
    #pragma unroll
    for (int e=1;e<E_;e++) if (pe[e] > pe[i1]) i1 = e;
    int i2 = (i1==0) ? 1 : 0;
    #pragma unroll
    for (int e=0;e<E_;e++) if (e!=i1 && pe[e] > pe[i2]) i2 = e;
    float wsum = pe[i1] + pe[i2];
    topw[t*2]   = pe[i1]/wsum;
    topw[t*2+1] = pe[i2]/wsum;
    topi[t*2] = i1; topi[t*2+1] = i2;
  }
}

// ------- deterministic per-expert compaction (single block) -------
__global__ __launch_bounds__(1024) void k_compact(const int* __restrict__ topi,
    const float* __restrict__ topw, int* __restrict__ gidx, float* __restrict__ asgw,
    int* __restrict__ slotmap, int* __restrict__ offs){
  int tid = threadIdx.x;
  __shared__ int wsum[16];
  __shared__ int sbase;
  if (tid==0) sbase = 0;
  __syncthreads();
  for (int e=0; e<E_; ++e){
    if (tid==0) offs[e] = sbase;
    __syncthreads();
    for (int c=0; c<2; ++c){
      int t = c*1024 + tid;
      int i1 = topi[2*t], i2 = topi[2*t+1];
      int which = (i1==e) ? 0 : ((i2==e) ? 1 : -1);
      bool flag = which >= 0;
      unsigned long long m = __ballot(flag);
      int lane = tid & 63, wid = tid >> 6;
      int rank = __popcll(m & ((1ull<<lane)-1ull));
      if (lane==0) wsum[wid] = __popcll(m);
      __syncthreads();
      int woff = 0;
      for (int w=0; w<wid; ++w) woff += wsum[w];
      int total = 0;
      for (int w=0; w<16; ++w) total += wsum[w];
      int pos = sbase + woff + rank;
      if (flag){
        gidx[pos] = t;
        asgw[pos] = topw[2*t+which];
        slotmap[2*t+which] = pos;
      }
      __syncthreads();
      if (tid==0) sbase += total;
      __syncthreads();
    }
  }
  if (tid==0) offs[E_] = sbase;
}

// ------- combine: x[t] += eo[slotA] + eo[slotB] -------
__global__ __launch_bounds__(128) void k_combine(const float* __restrict__ eo,
    const int* __restrict__ slotmap, float* __restrict__ x){
  int t = blockIdx.x; int d4 = threadIdx.x << 2;
  int s0 = slotmap[2*t], s1 = slotmap[2*t+1];
  float4 v  = *(float4*)(x + (size_t)t*D_ + d4);
  float4 e0 = *(const float4*)(eo + (size_t)s0*D_ + d4);
  float4 e1 = *(const float4*)(eo + (size_t)s1*D_ + d4);
  v.x += e0.x + e1.x; v.y += e0.y + e1.y; v.z += e0.z + e1.z; v.w += e0.w + e1.w;
  *(float4*)(x + (size_t)t*D_ + d4) = v;
}

// ---------------- aux loss ----------------
__global__ __launch_bounds__(256) void k_aux(const float* __restrict__ probs,
    const int* __restrict__ topi, float* __restrict__ dst, int first){
  float ps[E_]; int cnt[E_];
  #pragma unroll
  for (int e=0;e<E_;e++){ ps[e]=0.f; cnt[e]=0; }
  for (int t=threadIdx.x; t<NTOK; t+=256){
    #pragma unroll
    for (int e=0;e<E_;e++) ps[e] += probs[(size_t)t*E_ + e];
    int a_ = topi[t*2], b_ = topi[t*2+1];
    #pragma unroll
    for (int e=0;e<E_;e++) cnt[e] += (a_==e) + (b_==e);
  }
  int lane = threadIdx.x & 63, wid = threadIdx.x >> 6;
  __shared__ float rps[4][E_];
  __shared__ int   rcnt[4][E_];
  #pragma unroll
  for (int e=0;e<E_;e++){
    float v = ps[e]; int cc = cnt[e];
    #pragma unroll
    for (int off=32; off>=1; off>>=1){ v += __shfl_down(v, off); cc += __shfl_down(cc, off); }
    if (lane==0){ rps[wid][e]=v; rcnt[wid][e]=cc; }
  }
  __syncthreads();
  if (threadIdx.x==0){
    float aux = 0.f;
    #pragma unroll
    for (int e=0;e<E_;e++){
      float P = (rps[0][e]+rps[1][e]+rps[2][e]+rps[3][e]) * (1.0f/NTOK);
      float f = (float)(rcnt[0][e]+rcnt[1][e]+rcnt[2][e]+rcnt[3][e]) * (1.0f/(NTOK*2.0f));
      aux += f*P;
    }
    aux *= (float)E_;
    if (first) dst[0] = aux; else dst[0] += aux;
  }
}

// ---------------- host ----------------
extern "C" void kernel_launch(void* const* d_in, const int* in_sizes, int n_in,
                              void* d_out, int out_size, void* d_ws, size_t ws_size,
                              hipStream_t stream) {
  const int*   input_ids  = (const int*)  d_in[0];
  const float* tok_emb    = (const float*)d_in[1];
  const float* pos_emb    = (const float*)d_in[2];
  const float* norm1_w    = (const float*)d_in[3];
  const float* norm2_w    = (const float*)d_in[4];
  const float* in_proj_w  = (const float*)d_in[5];
  const float* conv_w     = (const float*)d_in[6];
  const float* conv_b     = (const float*)d_in[7];
  const float* x_proj_w   = (const float*)d_in[8];
  const float* dt_proj_w  = (const float*)d_in[9];
  const float* dt_proj_b  = (const float*)d_in[10];
  const float* A_log      = (const float*)d_in[11];
  const float* out_proj_w = (const float*)d_in[13];
  const float* router_w   = (const float*)d_in[14];
  const float* router_b   = (const float*)d_in[15];
  const float* w1         = (const float*)d_in[16];
  const float* b1         = (const float*)d_in[17];
  const float* w2         = (const float*)d_in[18];
  const float* b2         = (const float*)d_in[19];
  const float* final_norm = (const float*)d_in[20];
  const float* lm_head_w  = (const float*)d_in[21];
  float* out = (float*)d_out;

  float* ws = (float*)d_ws;
  float* x     = ws;
  float* xn    = x     + (size_t)NTOK*D_;
  float* xz    = xn    + (size_t)NTOK*D_;       // 4M
  float* xi    = xz    + (size_t)NTOK*2*DI_;    // 2M
  float* a     = xi    + (size_t)NTOK*DI_;      // 2M
  float* bb    = a     + (size_t)NTOK*DI_;      // 2M
  float* yact  = bb    + (size_t)NTOK*DI_;      // 2M
  float* h     = xz;   // alias: 4096 slots x 2048 = 8M floats over xz+xi+a
  float* eo    = bb;   // alias: 4096 slots x 512 = 2M floats
  float* delta = yact  + (size_t)NTOK*DI_;
  float* sdb   = delta + (size_t)NTOK*DS_;
  float* negA  = sdb   + NTOK;
  float* aprod = negA  + (size_t)DI_*DS_;
  float* yendb = aprod + NTOK*NCHUNK;
  float* probs = yendb + NTOK*NCHUNK;
  float* topw  = probs + (size_t)NTOK*E_;
  float* asgw  = topw  + (size_t)NTOK*2;
  int*   topi  = (int*)(asgw + (size_t)NTOK*2);
  int*   gidx  = topi + NTOK*2;
  int*   slotmap = gidx + NTOK*2;
  int*   offs  = slotmap + NTOK*2;

  float* aux_dst = out + (size_t)NTOK*VOCAB;

  k_embed<<<NTOK, 128, 0, stream>>>(input_ids, tok_emb, pos_emb, x);

  for (int l=0; l<2; ++l){
    // ---- mamba ----
    k_rmsnorm<<<NTOK, 128, 0, stream>>>(x, norm1_w + (size_t)l*D_, xn);
    gemm_f32<0><<<dim3(16,16), 256, 0, stream>>>(xn, in_proj_w + (size_t)l*2*DI_*D_,
                                                 xz, NTOK, 2*DI_, D_);
    k_conv<<<NTOK, 256, 0, stream>>>(xz, conv_w + (size_t)l*DI_*KC_, conv_b + (size_t)l*DI_, xi);
    k_xdbl<<<NTOK, 256, 0, stream>>>(xi, x_proj_w + (size_t)l*2*DS_*DI_,
                                     dt_proj_w + (size_t)l*DS_*DI_, dt_proj_b + (size_t)l*DS_,
                                     delta, sdb);
    k_negA<<<(DI_*DS_)/256, 256, 0, stream>>>(A_log + (size_t)l*DI_*DS_, negA);
    k_ab<<<NTOK, 256, 0, stream>>>(delta, sdb, negA, xi, a, bb);
    k_scan1<<<(NTOK*NCHUNK)/256, 256, 0, stream>>>(a, bb, aprod, yendb);
    k_scan2<<<(NTOK*NCHUNK)/256, 256, 0, stream>>>(a, bb, xz, aprod, yendb, yact);
    gemm_f32<2><<<dim3(16,4), 256, 0, stream>>>(yact, out_proj_w + (size_t)l*D_*DI_,
                                                x, NTOK, D_, DI_);
    // ---- moe (sparse top-2) ----
    k_rmsnorm<<<NTOK, 128, 0, stream>>>(x, norm2_w + (size_t)l*D_, xn);
    k_router<<<NTOK, 64, 0, stream>>>(xn, router_w + (size_t)l*E_*D_, router_b + (size_t)l*E_,
                                      probs, topw, topi);
    k_compact<<<1, 1024, 0, stream>>>(topi, topw, gidx, asgw, slotmap, offs);
    k_aux<<<1, 256, 0, stream>>>(probs, topi, aux_dst, l==0 ? 1 : 0);
    gemm_mfma<1,4><<<dim3(16,16,8), 256, 0, stream>>>(xn, w1 + (size_t)l*E_*DFF_*D_, h,
        b1 + (size_t)l*E_*DFF_, nullptr, gidx, offs, 0, DFF_, D_);
    gemm_mfma<2,4><<<dim3(16,4,8), 256, 0, stream>>>(h, w2 + (size_t)l*E_*D_*DFF_, eo,
        b2 + (size_t)l*E_*D_, asgw, nullptr, offs, 0, D_, DFF_);
    k_combine<<<NTOK, 128, 0, stream>>>(eo, slotmap, x);
  }

  // ---- head ----
  k_rmsnorm<<<NTOK, 128, 0, stream>>>(x, final_norm, xn);
  gemm_mfma<0,3><<<dim3(16,250,1), 256, 0, stream>>>(xn, lm_head_w, out, nullptr, nullptr,
                                                     nullptr, nullptr, NTOK, VOCAB, D_);
}

// Round 3
// 1170.640 us; speedup vs baseline: 5.6614x; 1.1648x over previous
//
#include <hip/hip_runtime.h>
#include <math.h>

#define S_    1024
#define D_    512
#define DI_   1024
#define DS_   16
#define KC_   4
#define E_    8
#define DFF_  2048
#define NTOK  2048     // B*S
#define VOCAB 32000
#define NCHUNK 16
#define CHL    64      // S_/NCHUNK

typedef unsigned short ushort;
typedef unsigned int   uint;
typedef __attribute__((ext_vector_type(8))) short short8;
typedef __attribute__((ext_vector_type(4))) float f32x4;

// ---------------- helpers ----------------
__device__ __forceinline__ float gelu_tanh(float x){
  float x3 = x*x*x;
  return 0.5f*x*(1.0f + tanhf(0.7978845608028654f*(x + 0.044715f*x3)));
}
__device__ __forceinline__ ushort f2bf_rnd(float f){
  uint u = __float_as_uint(f);
  return (ushort)((u + 0x8000u) >> 16);
}
__device__ __forceinline__ float bf2f(ushort h){
  return __uint_as_float(((uint)h) << 16);
}
__device__ __forceinline__ void split1(float f, ushort& h, ushort& l){
  h = f2bf_rnd(f);
  float fh = bf2f(h);
  l = (ushort)(__float_as_uint(f - fh) >> 16);
}

// ---------------- embed ----------------
__global__ __launch_bounds__(128) void k_embed(const int* __restrict__ ids,
    const float* __restrict__ tok, const float* __restrict__ pos, float* __restrict__ x){
  int t  = blockIdx.x;
  int d4 = threadIdx.x << 2;
  int s  = t & (S_-1);
  int id = ids[t];
  float4 tv = *(const float4*)(tok + (size_t)id*D_ + d4);
  float4 pv = *(const float4*)(pos + (size_t)s*D_ + d4);
  float4 o; o.x=tv.x+pv.x; o.y=tv.y+pv.y; o.z=tv.z+pv.z; o.w=tv.w+pv.w;
  *(float4*)(x + (size_t)t*D_ + d4) = o;
}

// ---------------- rmsnorm -> fp32 + split hi/lo ----------------
__global__ __launch_bounds__(128) void k_rmsnorm_split(const float* __restrict__ x,
    const float* __restrict__ w, float* __restrict__ out,
    ushort* __restrict__ oh, ushort* __restrict__ ol){
  int t = blockIdx.x;
  int d4 = threadIdx.x << 2;
  float4 v = *(const float4*)(x + (size_t)t*D_ + d4);
  float ss = v.x*v.x + v.y*v.y + v.z*v.z + v.w*v.w;
  #pragma unroll
  for (int off=32; off>=1; off>>=1) ss += __shfl_down(ss, off);
  __shared__ float sred[2];
  if ((threadIdx.x & 63) == 0) sred[threadIdx.x >> 6] = ss;
  __syncthreads();
  float total = sred[0] + sred[1];
  float scale = 1.0f / sqrtf(total * (1.0f/D_) + 1e-6f);
  float4 wv = *(const float4*)(w + d4);
  float4 o; o.x=v.x*scale*wv.x; o.y=v.y*scale*wv.y; o.z=v.z*scale*wv.z; o.w=v.w*scale*wv.w;
  *(float4*)(out + (size_t)t*D_ + d4) = o;
  ushort h0,h1,h2,h3,l0,l1,l2,l3;
  split1(o.x,h0,l0); split1(o.y,h1,l1); split1(o.z,h2,l2); split1(o.w,h3,l3);
  uint2 ph = make_uint2((uint)h0|((uint)h1<<16), (uint)h2|((uint)h3<<16));
  uint2 pl = make_uint2((uint)l0|((uint)l1<<16), (uint)l2|((uint)l3<<16));
  *(uint2*)(oh + (size_t)t*D_ + d4) = ph;
  *(uint2*)(ol + (size_t)t*D_ + d4) = pl;
}

// ---------------- fp32 -> hi/lo split (weights) ----------------
__global__ __launch_bounds__(256) void k_split(const float* __restrict__ s,
    ushort* __restrict__ dh, ushort* __restrict__ dl, int n4){
  int i = blockIdx.x*256 + threadIdx.x;
  if (i >= n4) return;
  float4 v = ((const float4*)s)[i];
  ushort h0,h1,h2,h3,l0,l1,l2,l3;
  split1(v.x,h0,l0); split1(v.y,h1,l1); split1(v.z,h2,l2); split1(v.w,h3,l3);
  ((uint2*)dh)[i] = make_uint2((uint)h0|((uint)h1<<16), (uint)h2|((uint)h3<<16));
  ((uint2*)dl)[i] = make_uint2((uint)l0|((uint)l1<<16), (uint)l2|((uint)l3<<16));
}

// ============ split-bf16 MFMA GEMM on pre-split operands ============
// C[M,N] = A[M,K] @ W[N,K]^T ; A,W given as bf16 hi/lo pairs
// EPI 0: dense,  Cb[row*N+col] = v                  (in_proj -> xz, lm_head -> out)
// EPI 1: sparse, A row via gidx; out split Ch/Cl = gelu(v+b)   (MoE w1 -> h)
// EPI 2: dense,  Cb += v                            (out_proj -> x residual)
// EPI 3: sparse, A row = slot; Cb[slot] = sw*(v+b)  (MoE w2 -> eo)
template<int EPI, int NT>
__global__ __launch_bounds__(256, 2) void gemm_mfma(
    const ushort* __restrict__ Ah, const ushort* __restrict__ Al,
    const ushort* __restrict__ Whb, const ushort* __restrict__ Wlb,
    float* __restrict__ Cb, ushort* __restrict__ Chh, ushort* __restrict__ Chl,
    const float* __restrict__ biasb, const float* __restrict__ slotw,
    const int* __restrict__ gidx, const int* __restrict__ offs,
    int M, int N, int K)
{
  int off = 0, cnt = M;
  if (EPI==1 || EPI==3){
    off = offs[blockIdx.z];
    cnt = offs[blockIdx.z+1] - off;
    if ((int)(blockIdx.x*128) >= cnt) return;
  }
  const size_t wbase = (size_t)blockIdx.z * N * K;
  const ushort* Wh = Whb + wbase;
  const ushort* Wl = Wlb + wbase;
  const float* bias = (EPI==1||EPI==3) ? (biasb + (size_t)blockIdx.z * N) : biasb;

  __shared__ ushort As_h[128][40];
  __shared__ ushort As_l[128][40];
  __shared__ ushort Ws_h[128][40];
  __shared__ ushort Ws_l[128][40];

  const int tid  = threadIdx.x;
  const int row0 = blockIdx.x * 128;
  const int col0 = blockIdx.y * 128;
  const int sr = tid >> 1;
  const int sh = (tid & 1) << 4;

  int aidx;
  if (EPI==1){ int lrr = row0 + sr; if (lrr > cnt-1) lrr = cnt-1; aidx = gidx[off + lrr]; }
  else if (EPI==3){ int lrr = row0 + sr; if (lrr > cnt-1) lrr = cnt-1; aidx = off + lrr; }
  else aidx = row0 + sr;
  const ushort* arh = Ah + (size_t)aidx*K;
  const ushort* arl = Al + (size_t)aidx*K;
  const ushort* wrh = Wh + (size_t)(col0 + sr)*K;
  const ushort* wrl = Wl + (size_t)(col0 + sr)*K;

  const int lane = tid & 63;
  const int wid  = tid >> 6;
  const int wrM  = (wid >> 1) * 64;
  const int wcN  = (wid & 1) * 64;
  const int lr   = lane & 15;
  const int ks   = lane >> 4;

  f32x4 zero = {0.f, 0.f, 0.f, 0.f};
  f32x4 acc[4][4];
  #pragma unroll
  for (int i=0;i<4;i++)
    #pragma unroll
    for (int j=0;j<4;j++) acc[i][j] = zero;

  short8 rah[2], ral[2], rwh[2], rwl[2];
  rah[0]=*(const short8*)(arh+sh); rah[1]=*(const short8*)(arh+sh+8);
  ral[0]=*(const short8*)(arl+sh); ral[1]=*(const short8*)(arl+sh+8);
  rwh[0]=*(const short8*)(wrh+sh); rwh[1]=*(const short8*)(wrh+sh+8);
  rwl[0]=*(const short8*)(wrl+sh); rwl[1]=*(const short8*)(wrl+sh+8);

  for (int kk=0; kk<K; kk+=32){
    __syncthreads();   // previous MFMA phase done reading LDS
    *(short8*)&As_h[sr][sh]   = rah[0];  *(short8*)&As_h[sr][sh+8] = rah[1];
    *(short8*)&As_l[sr][sh]   = ral[0];  *(short8*)&As_l[sr][sh+8] = ral[1];
    *(short8*)&Ws_h[sr][sh]   = rwh[0];  *(short8*)&Ws_h[sr][sh+8] = rwh[1];
    *(short8*)&Ws_l[sr][sh]   = rwl[0];  *(short8*)&Ws_l[sr][sh+8] = rwl[1];
    if (kk + 32 < K){
      int kn = kk + 32 + sh;
      rah[0]=*(const short8*)(arh+kn); rah[1]=*(const short8*)(arh+kn+8);
      ral[0]=*(const short8*)(arl+kn); ral[1]=*(const short8*)(arl+kn+8);
      rwh[0]=*(const short8*)(wrh+kn); rwh[1]=*(const short8*)(wrh+kn+8);
      rwl[0]=*(const short8*)(wrl+kn); rwl[1]=*(const short8*)(wrl+kn+8);
    }
    __syncthreads();

    short8 fah[4], fal[4], fbh[4], fbl[4];
    #pragma unroll
    for (int f=0; f<4; ++f){
      int rA = wrM + f*16 + lr;
      fah[f] = *(const short8*)&As_h[rA][ks*8];
      fal[f] = *(const short8*)&As_l[rA][ks*8];
      int rB = wcN + f*16 + lr;
      fbh[f] = *(const short8*)&Ws_h[rB][ks*8];
      fbl[f] = *(const short8*)&Ws_l[rB][ks*8];
    }
    #pragma unroll
    for (int i=0;i<4;i++)
      #pragma unroll
      for (int j=0;j<4;j++){
        f32x4 c = acc[i][j];
        if (NT==4) c = __builtin_amdgcn_mfma_f32_16x16x32_bf16(fal[i], fbl[j], c, 0,0,0);
        c = __builtin_amdgcn_mfma_f32_16x16x32_bf16(fal[i], fbh[j], c, 0,0,0);
        c = __builtin_amdgcn_mfma_f32_16x16x32_bf16(fah[i], fbl[j], c, 0,0,0);
        c = __builtin_amdgcn_mfma_f32_16x16x32_bf16(fah[i], fbh[j], c, 0,0,0);
        acc[i][j] = c;
      }
  }

  float bj[4];
  if (EPI==1 || EPI==3){
    #pragma unroll
    for (int j=0;j<4;j++) bj[j] = bias[col0 + wcN + j*16 + lr];
  }
  #pragma unroll
  for (int i=0;i<4;i++){
    #pragma unroll
    for (int jj=0;jj<4;jj++){
      int rt   = wrM + i*16 + ks*4 + jj;
      int grow = row0 + rt;
      if (EPI==0){
        float* cr = Cb + (size_t)grow*N + col0 + wcN + lr;
        #pragma unroll
        for (int j=0;j<4;j++) cr[j*16] = acc[i][j][jj];
      } else if (EPI==2){
        float* cr = Cb + (size_t)grow*N + col0 + wcN + lr;
        #pragma unroll
        for (int j=0;j<4;j++) cr[j*16] += acc[i][j][jj];
      } else if (EPI==1){
        if (grow < cnt){
          int slot = off + grow;
          size_t base = (size_t)slot*N + col0 + wcN + lr;
          #pragma unroll
          for (int j=0;j<4;j++){
            float g = gelu_tanh(acc[i][j][jj] + bj[j]);
            ushort hh, ll; split1(g, hh, ll);
            Chh[base + j*16] = hh; Chl[base + j*16] = ll;
          }
        }
      } else {
        if (grow < cnt){
          int slot = off + grow;
          float sw = slotw[slot];
          float* cr = Cb + (size_t)slot*N + col0 + wcN + lr;
          #pragma unroll
          for (int j=0;j<4;j++) cr[j*16] = sw*(acc[i][j][jj] + bj[j]);
        }
      }
    }
  }
}

// ---------------- causal depthwise conv (KC=4) + bias ----------------
__global__ __launch_bounds__(256) void k_conv(const float* __restrict__ xz,
    const float* __restrict__ cw, const float* __restrict__ cb, float* __restrict__ xi){
  int t = blockIdx.x;
  int b = t >> 10, s = t & (S_-1);
  int c0 = threadIdx.x << 2;
  float4 acc = *(const float4*)(cb + c0);
  #pragma unroll
  for (int k=0;k<KC_;k++){
    int ss = s - (KC_-1) + k;
    if (ss >= 0){
      float4 xv = *(const float4*)(xz + ((size_t)(b*S_+ss))*(2*DI_) + c0);
      acc.x += xv.x * cw[(c0+0)*KC_ + k];
      acc.y += xv.y * cw[(c0+1)*KC_ + k];
      acc.z += xv.z * cw[(c0+2)*KC_ + k];
      acc.w += xv.w * cw[(c0+3)*KC_ + k];
    }
  }
  *(float4*)(xi + (size_t)t*DI_ + c0) = acc;
}

// ------- per-token: B_param, delta=softplus(dt), sdb -------
__global__ __launch_bounds__(256) void k_xdbl(const float* __restrict__ xi,
    const float* __restrict__ xpw, const float* __restrict__ dtw,
    const float* __restrict__ dtb, float* __restrict__ delta, float* __restrict__ sdb){
  int t = blockIdx.x;
  __shared__ float xrow[DI_];
  __shared__ float outv[32];
  int tid = threadIdx.x;
  *(float4*)(xrow + (tid<<2)) = *(const float4*)(xi + (size_t)t*DI_ + (tid<<2));
  __syncthreads();
  int wid = tid >> 6, lane = tid & 63;
  #pragma unroll
  for (int oi=0; oi<8; ++oi){
    int o = wid*8 + oi;
    const float* wr = (o < 16) ? (xpw + (size_t)(DS_ + o)*DI_) : (dtw + (size_t)(o-16)*DI_);
    float sum = 0.f;
    #pragma unroll
    for (int j=0;j<16;j++) sum += xrow[lane + 64*j] * wr[lane + 64*j];
    #pragma unroll
    for (int off=32; off>=1; off>>=1) sum += __shfl_down(sum, off);
    if (lane == 0) outv[o] = sum;
  }
  __syncthreads();
  if (tid < DS_){
    float d  = outv[16+tid] + dtb[tid];
    float sp = fmaxf(d, 0.f) + log1pf(expf(-fabsf(d)));
    delta[(size_t)t*DS_ + tid] = sp;
    float pr = sp * outv[tid];
    #pragma unroll
    for (int off=8; off>=1; off>>=1) pr += __shfl_down(pr, off);
    if (tid == 0) sdb[t] = pr;
  }
}

__global__ __launch_bounds__(256) void k_negA(const float* __restrict__ Alog, float* __restrict__ negA){
  int i = blockIdx.x*256 + threadIdx.x;
  negA[i] = -expf(Alog[i]);
}

__global__ __launch_bounds__(256) void k_ab(const float* __restrict__ delta,
    const float* __restrict__ sdb, const float* __restrict__ negA,
    const float* __restrict__ xi, float* __restrict__ a, float* __restrict__ bb){
  int t = blockIdx.x;
  __shared__ float dl[DS_];
  if (threadIdx.x < DS_) dl[threadIdx.x] = delta[(size_t)t*DS_ + threadIdx.x];
  __syncthreads();
  float s = sdb[t];
  int di0 = threadIdx.x << 2;
  float4 xv = *(const float4*)(xi + (size_t)t*DI_ + di0);
  float av[4];
  #pragma unroll
  for (int i=0;i<4;i++){
    const float* nA = negA + (size_t)(di0+i)*DS_;
    float sum = 0.f;
    #pragma unroll
    for (int ds=0; ds<DS_; ds++) sum += expf(dl[ds] * nA[ds]);
    av[i] = sum;
  }
  *(float4*)(a + (size_t)t*DI_ + di0) = make_float4(av[0],av[1],av[2],av[3]);
  float4 bv; bv.x=xv.x*s; bv.y=xv.y*s; bv.z=xv.z*s; bv.w=xv.w*s;
  *(float4*)(bb + (size_t)t*DI_ + di0) = bv;
}

__global__ __launch_bounds__(256) void k_scan1(const float* __restrict__ a,
    const float* __restrict__ bb, float* __restrict__ aprod, float* __restrict__ yend){
  int g  = blockIdx.x*256 + threadIdx.x;
  int di = g & (DI_-1);
  int c  = (g >> 10) & (NCHUNK-1);
  int b  = g >> 14;
  float ap = 1.f, y = 0.f;
  size_t base = ((size_t)b*S_ + (size_t)c*CHL)*DI_ + di;
  #pragma unroll 4
  for (int i=0;i<CHL;i++){
    float at = a[base + (size_t)i*DI_], bt = bb[base + (size_t)i*DI_];
    y = at*y + bt; ap *= at;
  }
  aprod[g] = ap; yend[g] = y;
}

// scan phase 2 fused with silu gating; emits yact pre-split to bf16 hi/lo
__global__ __launch_bounds__(256) void k_scan2(const float* __restrict__ a,
    const float* __restrict__ bb, const float* __restrict__ xz,
    const float* __restrict__ aprod, const float* __restrict__ yend,
    ushort* __restrict__ yh, ushort* __restrict__ yl){
  int g  = blockIdx.x*256 + threadIdx.x;
  int di = g & (DI_-1);
  int c  = (g >> 10) & (NCHUNK-1);
  int b  = g >> 14;
  float y = 0.f;
  for (int j=0;j<c;j++){
    int gg = ((b*NCHUNK + j) << 10) + di;
    y = aprod[gg]*y + yend[gg];
  }
  size_t base = ((size_t)b*S_ + (size_t)c*CHL)*DI_ + di;
  #pragma unroll 4
  for (int i=0;i<CHL;i++){
    float at = a[base + (size_t)i*DI_], bt = bb[base + (size_t)i*DI_];
    y = at*y + bt;
    float z = xz[((size_t)(b*S_ + c*CHL + i))*(2*DI_) + DI_ + di];
    float sil = z / (1.f + expf(-z));
    float v = y * sil;
    ushort hh, ll; split1(v, hh, ll);
    yh[base + (size_t)i*DI_] = hh;
    yl[base + (size_t)i*DI_] = ll;
  }
}

// ------- router -------
__global__ __launch_bounds__(64) void k_router(const float* __restrict__ xn,
    const float* __restrict__ rw, const float* __restrict__ rb,
    float* __restrict__ probs, float* __restrict__ topw, int* __restrict__ topi){
  int t = blockIdx.x, lane = threadIdx.x;
  float xv[8];
  #pragma unroll
  for (int j=0;j<8;j++) xv[j] = xn[(size_t)t*D_ + lane + 64*j];
  __shared__ float lg[E_];
  #pragma unroll
  for (int e=0;e<E_;e++){
    float s = 0.f;
    #pragma unroll
    for (int j=0;j<8;j++) s += xv[j]*rw[(size_t)e*D_ + lane + 64*j];
    #pragma unroll
    for (int off=32; off>=1; off>>=1) s += __shfl_down(s, off);
    if (lane==0) lg[e] = s + rb[e];
  }
  __syncthreads();
  if (lane==0){
    float mx = lg[0];
    #pragma unroll
    for (int e=1;e<E_;e++) mx = fmaxf(mx, lg[e]);
    float pe[E_]; float sum = 0.f;
    #pragma unroll
    for (int e=0;e<E_;e++){ pe[e] = expf(lg[e]-mx); sum += pe[e]; }
    #pragma unroll
    for (int e=0;e<E_;e++){ pe[e] /= sum; probs[(size_t)t*E_ + e] = pe[e]; }
    int i1 = 0;
    #pragma unroll
    for (int e=1;e<E_;e++) if (pe[e] > pe[i1]) i1 = e;
    int i2 = (i1==0) ? 1 : 0;
    #pragma unroll
    for (int e=0;e<E_;e++) if (e!=i1 && pe[e] > pe[i2]) i2 = e;
    float wsum = pe[i1] + pe[i2];
    topw[t*2]   = pe[i1]/wsum;
    topw[t*2+1] = pe[i2]/wsum;
    topi[t*2] = i1; topi[t*2+1] = i2;
  }
}

// ------- compaction: warp-per-expert, two passes, deterministic -------
__global__ __launch_bounds__(512) void k_compact(const int* __restrict__ topi,
    const float* __restrict__ topw, int* __restrict__ gidx, float* __restrict__ asgw,
    int* __restrict__ slotmap, int* __restrict__ offs){
  int e = threadIdx.x >> 6, lane = threadIdx.x & 63;
  __shared__ int counts[E_];
  int cnt = 0;
  for (int c=0; c<NTOK/64; ++c){
    int t = c*64 + lane;
    bool flag = (topi[2*t]==e) || (topi[2*t+1]==e);
    unsigned long long m = __ballot(flag);
    cnt += __popcll(m);
  }
  if (lane==0) counts[e] = cnt;
  __syncthreads();
  int base = 0;
  for (int i=0;i<e;i++) base += counts[i];
  if (lane==0) offs[e] = base;
  if (threadIdx.x==0){
    int tot=0;
    for (int i=0;i<E_;i++) tot += counts[i];
    offs[E_] = tot;
  }
  int run = base;
  for (int c=0; c<NTOK/64; ++c){
    int t = c*64 + lane;
    int which = (topi[2*t]==e) ? 0 : ((topi[2*t+1]==e) ? 1 : -1);
    bool flag = which >= 0;
    unsigned long long m = __ballot(flag);
    int rank = __popcll(m & ((1ull<<lane)-1ull));
    if (flag){
      int pos = run + rank;
      gidx[pos] = t;
      asgw[pos] = topw[2*t+which];
      slotmap[2*t+which] = pos;
    }
    run += __popcll(m);
  }
}

// ------- combine: x[t] += eo[slotA] + eo[slotB] -------
__global__ __launch_bounds__(128) void k_combine(const float* __restrict__ eo,
    const int* __restrict__ slotmap, float* __restrict__ x){
  int t = blockIdx.x; int d4 = threadIdx.x << 2;
  int s0 = slotmap[2*t], s1 = slotmap[2*t+1];
  float4 v  = *(float4*)(x + (size_t)t*D_ + d4);
  float4 e0 = *(const float4*)(eo + (size_t)s0*D_ + d4);
  float4 e1 = *(const float4*)(eo + (size_t)s1*D_ + d4);
  v.x += e0.x + e1.x; v.y += e0.y + e1.y; v.z += e0.z + e1.z; v.w += e0.w + e1.w;
  *(float4*)(x + (size_t)t*D_ + d4) = v;
}

// ---------------- aux loss ----------------
__global__ __launch_bounds__(256) void k_aux(const float* __restrict__ probs,
    const int* __restrict__ topi, float* __restrict__ dst, int first){
  float ps[E_]; int cnt[E_];
  #pragma unroll
  for (int e=0;e<E_;e++){ ps[e]=0.f; cnt[e]=0; }
  for (int t=threadIdx.x; t<NTOK; t+=256){
    #pragma unroll
    for (int e=0;e<E_;e++) ps[e] += probs[(size_t)t*E_ + e];
    int a_ = topi[t*2], b_ = topi[t*2+1];
    #pragma unroll
    for (int e=0;e<E_;e++) cnt[e] += (a_==e) + (b_==e);
  }
  int lane = threadIdx.x & 63, wid = threadIdx.x >> 6;
  __shared__ float rps[4][E_];
  __shared__ int   rcnt[4][E_];
  #pragma unroll
  for (int e=0;e<E_;e++){
    float v = ps[e]; int cc = cnt[e];
    #pragma unroll
    for (int off=32; off>=1; off>>=1){ v += __shfl_down(v, off); cc += __shfl_down(cc, off); }
    if (lane==0){ rps[wid][e]=v; rcnt[wid][e]=cc; }
  }
  __syncthreads();
  if (threadIdx.x==0){
    float aux = 0.f;
    #pragma unroll
    for (int e=0;e<E_;e++){
      float P = (rps[0][e]+rps[1][e]+rps[2][e]+rps[3][e]) * (1.0f/NTOK);
      float f = (float)(rcnt[0][e]+rcnt[1][e]+rcnt[2][e]+rcnt[3][e]) * (1.0f/(NTOK*2.0f));
      aux += f*P;
    }
    aux *= (float)E_;
    if (first) dst[0] = aux; else dst[0] += aux;
  }
}

// ---------------- host ----------------
extern "C" void kernel_launch(void* const* d_in, const int* in_sizes, int n_in,
                              void* d_out, int out_size, void* d_ws, size_t ws_size,
                              hipStream_t stream) {
  const int*   input_ids  = (const int*)  d_in[0];
  const float* tok_emb    = (const float*)d_in[1];
  const float* pos_emb    = (const float*)d_in[2];
  const float* norm1_w    = (const float*)d_in[3];
  const float* norm2_w    = (const float*)d_in[4];
  const float* in_proj_w  = (const float*)d_in[5];
  const float* conv_w     = (const float*)d_in[6];
  const float* conv_b     = (const float*)d_in[7];
  const float* x_proj_w   = (const float*)d_in[8];
  const float* dt_proj_w  = (const float*)d_in[9];
  const float* dt_proj_b  = (const float*)d_in[10];
  const float* A_log      = (const float*)d_in[11];
  const float* out_proj_w = (const float*)d_in[13];
  const float* router_w   = (const float*)d_in[14];
  const float* router_b   = (const float*)d_in[15];
  const float* w1         = (const float*)d_in[16];
  const float* b1         = (const float*)d_in[17];
  const float* w2         = (const float*)d_in[18];
  const float* b2         = (const float*)d_in[19];
  const float* final_norm = (const float*)d_in[20];
  const float* lm_head_w  = (const float*)d_in[21];
  float* out = (float*)d_out;

  // ---- workspace layout (floats) ----
  float* ws = (float*)d_ws;
  float*  x     = ws;                                    // 1,048,576
  float*  xn    = x + 1048576;                           // 1,048,576
  ushort* xnh   = (ushort*)(xn + 1048576);               // 1,048,576 us
  ushort* xnl   = xnh + 1048576;                         // 1,048,576 us
  float*  region1 = (float*)(xnl + 1048576);             // 8,388,608 f
  float*  xz    = region1;                               // 4,194,304
  float*  xi    = region1 + 4194304;                     // 2,097,152
  float*  a     = region1 + 6291456;                     // 2,097,152
  float*  bb    = region1 + 8388608;                     // 2,097,152
  ushort* yh    = (ushort*)(bb + 2097152);               // 2,097,152 us
  ushort* yl    = yh + 2097152;                          // 2,097,152 us
  float*  wsp   = (float*)(yl + 2097152);                // 8,388,608 f (weight splits)
  float*  delta = wsp + 8388608;                         // 32,768
  float*  sdb   = delta + 32768;                         // 2,048
  float*  negA  = sdb + 2048;                            // 16,384
  float*  aprod = negA + 16384;                          // 32,768
  float*  yendb = aprod + 32768;                         // 32,768
  float*  probs = yendb + 32768;                         // 16,384
  float*  topw  = probs + 16384;                         // 4,096
  float*  asgw  = topw + 4096;                           // 4,096
  int*    topi  = (int*)(asgw + 4096);                   // 4,096
  int*    gidx  = topi + 4096;                           // 4,096
  int*    slotmap = gidx + 4096;                         // 4,096
  int*    offs  = slotmap + 4096;                        // 16

  // aliases (dead-region reuse)
  ushort* hh  = (ushort*)region1;        // h split: 8,388,608 us each
  ushort* hl  = hh + 8388608;
  float*  eo  = bb;                      // 4096 x 512
  ushort* lmh = (ushort*)region1;        // lm_head split: 16,384,000 us each
  ushort* lml = (ushort*)wsp;
  ushort* wh  = (ushort*)wsp;            // per-layer weight split (hi), lo follows

  float* aux_dst = out + (size_t)NTOK*VOCAB;

  k_embed<<<NTOK, 128, 0, stream>>>(input_ids, tok_emb, pos_emb, x);

  for (int l=0; l<2; ++l){
    // ---- mamba ----
    k_rmsnorm_split<<<NTOK, 128, 0, stream>>>(x, norm1_w + (size_t)l*D_, xn, xnh, xnl);
    {
      int ne = 2*DI_*D_;                 // 2,097,152
      ushort* wl_ = wh + ne;
      k_split<<<ne/1024, 256, 0, stream>>>(in_proj_w + (size_t)l*ne, wh, wl_, ne/4);
      gemm_mfma<0,4><<<dim3(16,16,1), 256, 0, stream>>>(xnh, xnl, wh, wl_,
          xz, nullptr, nullptr, nullptr, nullptr, nullptr, nullptr, NTOK, 2*DI_, D_);
    }
    k_conv<<<NTOK, 256, 0, stream>>>(xz, conv_w + (size_t)l*DI_*KC_, conv_b + (size_t)l*DI_, xi);
    k_xdbl<<<NTOK, 256, 0, stream>>>(xi, x_proj_w + (size_t)l*2*DS_*DI_,
                                     dt_proj_w + (size_t)l*DS_*DI_, dt_proj_b + (size_t)l*DS_,
                                     delta, sdb);
    k_negA<<<(DI_*DS_)/256, 256, 0, stream>>>(A_log + (size_t)l*DI_*DS_, negA);
    k_ab<<<NTOK, 256, 0, stream>>>(delta, sdb, negA, xi, a, bb);
    k_scan1<<<(NTOK*NCHUNK)/256, 256, 0, stream>>>(a, bb, aprod, yendb);
    k_scan2<<<(NTOK*NCHUNK)/256, 256, 0, stream>>>(a, bb, xz, aprod, yendb, yh, yl);
    {
      int ne = D_*DI_;                   // 524,288
      ushort* wl_ = wh + ne;
      k_split<<<ne/1024, 256, 0, stream>>>(out_proj_w + (size_t)l*ne, wh, wl_, ne/4);
      gemm_mfma<2,4><<<dim3(16,4,1), 256, 0, stream>>>(yh, yl, wh, wl_,
          x, nullptr, nullptr, nullptr, nullptr, nullptr, nullptr, NTOK, D_, DI_);
    }
    // ---- moe (sparse top-2) ----
    k_rmsnorm_split<<<NTOK, 128, 0, stream>>>(x, norm2_w + (size_t)l*D_, xn, xnh, xnl);
    k_router<<<NTOK, 64, 0, stream>>>(xn, router_w + (size_t)l*E_*D_, router_b + (size_t)l*E_,
                                      probs, topw, topi);
    k_compact<<<1, 512, 0, stream>>>(topi, topw, gidx, asgw, slotmap, offs);
    k_aux<<<1, 256, 0, stream>>>(probs, topi, aux_dst, l==0 ? 1 : 0);
    {
      int ne = E_*DFF_*D_;               // 8,388,608
      ushort* wl_ = wh + ne;
      k_split<<<ne/1024, 256, 0, stream>>>(w1 + (size_t)l*ne, wh, wl_, ne/4);
      gemm_mfma<1,4><<<dim3(16,16,8), 256, 0, stream>>>(xnh, xnl, wh, wl_,
          nullptr, hh, hl, b1 + (size_t)l*E_*DFF_, nullptr, gidx, offs, 0, DFF_, D_);
    }
    {
      int ne = E_*D_*DFF_;               // 8,388,608
      ushort* wl_ = wh + ne;
      k_split<<<ne/1024, 256, 0, stream>>>(w2 + (size_t)l*ne, wh, wl_, ne/4);
      gemm_mfma<3,4><<<dim3(16,4,8), 256, 0, stream>>>(hh, hl, wh, wl_,
          eo, nullptr, nullptr, b2 + (size_t)l*E_*D_, asgw, nullptr, offs, 0, D_, DFF_);
    }
    k_combine<<<NTOK, 128, 0, stream>>>(eo, slotmap, x);
  }

  // ---- head ----
  k_rmsnorm_split<<<NTOK, 128, 0, stream>>>(x, final_norm, xn, xnh, xnl);
  {
    int ne = VOCAB*D_;                   // 16,384,000
    k_split<<<ne/1024, 256, 0, stream>>>(lm_head_w, lmh, lml, ne/4);
    gemm_mfma<0,3><<<dim3(16,250,1), 256, 0, stream>>>(xnh, xnl, lmh, lml,
        out, nullptr, nullptr, nullptr, nullptr, nullptr, nullptr, NTOK, VOCAB, D_);
  }
}

// Round 4
// 1045.851 us; speedup vs baseline: 6.3369x; 1.1193x over previous
//
#include <hip/hip_runtime.h>
#include <math.h>

#define S_    1024
#define D_    512
#define DI_   1024
#define DS_   16
#define KC_   4
#define E_    8
#define DFF_  2048
#define NTOK  2048     // B*S
#define VOCAB 32000
#define NCHUNK 16
#define CHL    64      // S_/NCHUNK

typedef unsigned short ushort;
typedef unsigned int   uint;
typedef __attribute__((ext_vector_type(8))) short short8;
typedef __attribute__((ext_vector_type(4))) float f32x4;

// ---------------- helpers ----------------
__device__ __forceinline__ float gelu_tanh(float x){
  float x3 = x*x*x;
  return 0.5f*x*(1.0f + tanhf(0.7978845608028654f*(x + 0.044715f*x3)));
}
__device__ __forceinline__ ushort f2bf_rnd(float f){
  uint u = __float_as_uint(f);
  return (ushort)((u + 0x8000u) >> 16);
}
__device__ __forceinline__ float bf2f(ushort h){
  return __uint_as_float(((uint)h) << 16);
}
__device__ __forceinline__ void split1(float f, ushort& h, ushort& l){
  h = f2bf_rnd(f);
  float fh = bf2f(h);
  l = (ushort)(__float_as_uint(f - fh) >> 16);
}

// ---------------- embed ----------------
__global__ __launch_bounds__(128) void k_embed(const int* __restrict__ ids,
    const float* __restrict__ tok, const float* __restrict__ pos, float* __restrict__ x){
  int t  = blockIdx.x;
  int d4 = threadIdx.x << 2;
  int s  = t & (S_-1);
  int id = ids[t];
  float4 tv = *(const float4*)(tok + (size_t)id*D_ + d4);
  float4 pv = *(const float4*)(pos + (size_t)s*D_ + d4);
  float4 o; o.x=tv.x+pv.x; o.y=tv.y+pv.y; o.z=tv.z+pv.z; o.w=tv.w+pv.w;
  *(float4*)(x + (size_t)t*D_ + d4) = o;
}

// ---------------- rmsnorm -> fp32 + split hi/lo ----------------
__global__ __launch_bounds__(128) void k_rmsnorm_split(const float* __restrict__ x,
    const float* __restrict__ w, float* __restrict__ out,
    ushort* __restrict__ oh, ushort* __restrict__ ol){
  int t = blockIdx.x;
  int d4 = threadIdx.x << 2;
  float4 v = *(const float4*)(x + (size_t)t*D_ + d4);
  float ss = v.x*v.x + v.y*v.y + v.z*v.z + v.w*v.w;
  #pragma unroll
  for (int off=32; off>=1; off>>=1) ss += __shfl_down(ss, off);
  __shared__ float sred[2];
  if ((threadIdx.x & 63) == 0) sred[threadIdx.x >> 6] = ss;
  __syncthreads();
  float total = sred[0] + sred[1];
  float scale = 1.0f / sqrtf(total * (1.0f/D_) + 1e-6f);
  float4 wv = *(const float4*)(w + d4);
  float4 o; o.x=v.x*scale*wv.x; o.y=v.y*scale*wv.y; o.z=v.z*scale*wv.z; o.w=v.w*scale*wv.w;
  *(float4*)(out + (size_t)t*D_ + d4) = o;
  ushort h0,h1,h2,h3,l0,l1,l2,l3;
  split1(o.x,h0,l0); split1(o.y,h1,l1); split1(o.z,h2,l2); split1(o.w,h3,l3);
  uint2 ph = make_uint2((uint)h0|((uint)h1<<16), (uint)h2|((uint)h3<<16));
  uint2 pl = make_uint2((uint)l0|((uint)l1<<16), (uint)l2|((uint)l3<<16));
  *(uint2*)(oh + (size_t)t*D_ + d4) = ph;
  *(uint2*)(ol + (size_t)t*D_ + d4) = pl;
}

// ---------------- fp32 -> hi/lo split (weights) ----------------
__global__ __launch_bounds__(256) void k_split(const float* __restrict__ s,
    ushort* __restrict__ dh, ushort* __restrict__ dl, int n4){
  int i = blockIdx.x*256 + threadIdx.x;
  if (i >= n4) return;
  float4 v = ((const float4*)s)[i];
  ushort h0,h1,h2,h3,l0,l1,l2,l3;
  split1(v.x,h0,l0); split1(v.y,h1,l1); split1(v.z,h2,l2); split1(v.w,h3,l3);
  ((uint2*)dh)[i] = make_uint2((uint)h0|((uint)h1<<16), (uint)h2|((uint)h3<<16));
  ((uint2*)dl)[i] = make_uint2((uint)l0|((uint)l1<<16), (uint)l2|((uint)l3<<16));
}

// ---------------- fp32 -> bf16 hi only (lm_head weights) ----------------
__global__ __launch_bounds__(256) void k_bf16(const float* __restrict__ s,
    ushort* __restrict__ dh, int n4){
  int i = blockIdx.x*256 + threadIdx.x;
  if (i >= n4) return;
  float4 v = ((const float4*)s)[i];
  ushort h0 = f2bf_rnd(v.x), h1 = f2bf_rnd(v.y), h2 = f2bf_rnd(v.z), h3 = f2bf_rnd(v.w);
  ((uint2*)dh)[i] = make_uint2((uint)h0|((uint)h1<<16), (uint)h2|((uint)h3<<16));
}

// ============ split-bf16 MFMA GEMM on pre-split operands ============
// C[M,N] = A[M,K] @ W[N,K]^T ; A,W as bf16 hi/lo pairs (lo unused if NT==1)
// EPI 0: dense,  Cb[row*N+col] = v                 (in_proj -> xz, lm_head -> out)
// EPI 1: sparse, A row via gidx; Ch/Cl = split(gelu(v+b))      (MoE w1 -> h)
// EPI 2: dense,  atomicAdd Cb[row*N+col] += v      (out_proj, split-K)
// EPI 3: sparse, A row = slot; atomicAdd Cb[gidx[slot]*N+col] += sw*(v [+b if ks==0])  (MoE w2, split-K)
template<int EPI, int NT, int KSP>
__global__ __launch_bounds__(256, 2) void gemm_mfma(
    const ushort* __restrict__ Ah, const ushort* __restrict__ Al,
    const ushort* __restrict__ Whb, const ushort* __restrict__ Wlb,
    float* __restrict__ Cb, ushort* __restrict__ Chh, ushort* __restrict__ Chl,
    const float* __restrict__ biasb, const float* __restrict__ slotw,
    const int* __restrict__ gidx, const int* __restrict__ offs,
    int M, int N, int K)
{
  int e, ks;
  if (KSP > 1){ e = blockIdx.z / KSP; ks = blockIdx.z % KSP; }
  else        { e = blockIdx.z;       ks = 0; }
  int off = 0, cnt = M;
  if (EPI==1 || EPI==3){
    off = offs[e];
    cnt = offs[e+1] - off;
    if ((int)(blockIdx.x*128) >= cnt) return;
  }
  const size_t wbase = (size_t)((EPI==1||EPI==3) ? e : 0) * N * K;
  const ushort* Wh = Whb + wbase;
  const ushort* Wl = Wlb + wbase;
  const float* bias = (EPI==1||EPI==3) ? (biasb + (size_t)e * N) : biasb;

  __shared__ ushort As_h[128][40];
  __shared__ ushort Ws_h[128][40];
  __shared__ ushort As_l[(NT>1)?128:1][40];
  __shared__ ushort Ws_l[(NT>1)?128:1][40];

  const int tid  = threadIdx.x;
  const int row0 = blockIdx.x * 128;
  const int col0 = blockIdx.y * 128;
  const int sr = tid >> 1;
  const int sh = (tid & 1) << 4;

  int aidx;
  if (EPI==1){ int lrr = row0 + sr; if (lrr > cnt-1) lrr = cnt-1; aidx = gidx[off + lrr]; }
  else if (EPI==3){ int lrr = row0 + sr; if (lrr > cnt-1) lrr = cnt-1; aidx = off + lrr; }
  else aidx = row0 + sr;
  const ushort* arh = Ah + (size_t)aidx*K;
  const ushort* arl = Al + (size_t)aidx*K;
  const ushort* wrh = Wh + (size_t)(col0 + sr)*K;
  const ushort* wrl = Wl + (size_t)(col0 + sr)*K;

  const int lane = tid & 63;
  const int wid  = tid >> 6;
  const int wrM  = (wid >> 1) * 64;
  const int wcN  = (wid & 1) * 64;
  const int lr   = lane & 15;
  const int kq   = lane >> 4;

  f32x4 zero = {0.f, 0.f, 0.f, 0.f};
  f32x4 acc[4][4];
  #pragma unroll
  for (int i=0;i<4;i++)
    #pragma unroll
    for (int j=0;j<4;j++) acc[i][j] = zero;

  const int k0 = ks * (K / KSP);
  const int k1 = k0 + (K / KSP);

  short8 rah[2], ral[2], rwh[2], rwl[2];
  rah[0]=*(const short8*)(arh+k0+sh); rah[1]=*(const short8*)(arh+k0+sh+8);
  rwh[0]=*(const short8*)(wrh+k0+sh); rwh[1]=*(const short8*)(wrh+k0+sh+8);
  if (NT>1){
    ral[0]=*(const short8*)(arl+k0+sh); ral[1]=*(const short8*)(arl+k0+sh+8);
    rwl[0]=*(const short8*)(wrl+k0+sh); rwl[1]=*(const short8*)(wrl+k0+sh+8);
  }

  for (int kk=k0; kk<k1; kk+=32){
    __syncthreads();   // previous MFMA phase done reading LDS
    *(short8*)&As_h[sr][sh]   = rah[0];  *(short8*)&As_h[sr][sh+8] = rah[1];
    *(short8*)&Ws_h[sr][sh]   = rwh[0];  *(short8*)&Ws_h[sr][sh+8] = rwh[1];
    if (NT>1){
      *(short8*)&As_l[sr][sh]   = ral[0];  *(short8*)&As_l[sr][sh+8] = ral[1];
      *(short8*)&Ws_l[sr][sh]   = rwl[0];  *(short8*)&Ws_l[sr][sh+8] = rwl[1];
    }
    if (kk + 32 < k1){
      int kn = kk + 32 + sh;
      rah[0]=*(const short8*)(arh+kn); rah[1]=*(const short8*)(arh+kn+8);
      rwh[0]=*(const short8*)(wrh+kn); rwh[1]=*(const short8*)(wrh+kn+8);
      if (NT>1){
        ral[0]=*(const short8*)(arl+kn); ral[1]=*(const short8*)(arl+kn+8);
        rwl[0]=*(const short8*)(wrl+kn); rwl[1]=*(const short8*)(wrl+kn+8);
      }
    }
    __syncthreads();

    short8 fah[4], fal[4], fbh[4], fbl[4];
    #pragma unroll
    for (int f=0; f<4; ++f){
      int rA = wrM + f*16 + lr;
      fah[f] = *(const short8*)&As_h[rA][kq*8];
      int rB = wcN + f*16 + lr;
      fbh[f] = *(const short8*)&Ws_h[rB][kq*8];
      if (NT>1){
        fal[f] = *(const short8*)&As_l[rA][kq*8];
        fbl[f] = *(const short8*)&Ws_l[rB][kq*8];
      }
    }
    #pragma unroll
    for (int i=0;i<4;i++)
      #pragma unroll
      for (int j=0;j<4;j++){
        f32x4 c = acc[i][j];
        if (NT==4) c = __builtin_amdgcn_mfma_f32_16x16x32_bf16(fal[i], fbl[j], c, 0,0,0);
        if (NT>1){
          c = __builtin_amdgcn_mfma_f32_16x16x32_bf16(fal[i], fbh[j], c, 0,0,0);
          c = __builtin_amdgcn_mfma_f32_16x16x32_bf16(fah[i], fbl[j], c, 0,0,0);
        }
        c = __builtin_amdgcn_mfma_f32_16x16x32_bf16(fah[i], fbh[j], c, 0,0,0);
        acc[i][j] = c;
      }
  }

  float bj[4];
  if (EPI==1 || EPI==3){
    #pragma unroll
    for (int j=0;j<4;j++) bj[j] = bias[col0 + wcN + j*16 + lr];
  }
  #pragma unroll
  for (int i=0;i<4;i++){
    #pragma unroll
    for (int jj=0;jj<4;jj++){
      int rt   = wrM + i*16 + kq*4 + jj;
      int grow = row0 + rt;
      if (EPI==0){
        float* cr = Cb + (size_t)grow*N + col0 + wcN + lr;
        #pragma unroll
        for (int j=0;j<4;j++) cr[j*16] = acc[i][j][jj];
      } else if (EPI==2){
        float* cr = Cb + (size_t)grow*N + col0 + wcN + lr;
        #pragma unroll
        for (int j=0;j<4;j++) atomicAdd(&cr[j*16], acc[i][j][jj]);
      } else if (EPI==1){
        if (grow < cnt){
          int slot = off + grow;
          size_t base = (size_t)slot*N + col0 + wcN + lr;
          #pragma unroll
          for (int j=0;j<4;j++){
            float g = gelu_tanh(acc[i][j][jj] + bj[j]);
            ushort hh, ll; split1(g, hh, ll);
            Chh[base + j*16] = hh; Chl[base + j*16] = ll;
          }
        }
      } else {
        if (grow < cnt){
          int slot = off + grow;
          int tok  = gidx[slot];
          float sw = slotw[slot];
          float* cr = Cb + (size_t)tok*N + col0 + wcN + lr;
          #pragma unroll
          for (int j=0;j<4;j++){
            float v = acc[i][j][jj];
            if (ks==0) v += bj[j];
            atomicAdd(&cr[j*16], sw*v);
          }
        }
      }
    }
  }
}

// ------ fused: causal depthwise conv (KC=4)+bias -> xi; then x_dbl B/delta/sdb ------
__global__ __launch_bounds__(256) void k_convdt(const float* __restrict__ xz,
    const float* __restrict__ cw, const float* __restrict__ cb,
    const float* __restrict__ xpw, const float* __restrict__ dtw,
    const float* __restrict__ dtb,
    float* __restrict__ xi, float* __restrict__ delta, float* __restrict__ sdb){
  int t = blockIdx.x;
  int b = t >> 10, s = t & (S_-1);
  int tid = threadIdx.x;
  int c0 = tid << 2;
  __shared__ float xrow[DI_];
  __shared__ float outv[32];
  float4 acc = *(const float4*)(cb + c0);
  #pragma unroll
  for (int k=0;k<KC_;k++){
    int ss = s - (KC_-1) + k;
    if (ss >= 0){
      float4 xv = *(const float4*)(xz + ((size_t)(b*S_+ss))*(2*DI_) + c0);
      acc.x += xv.x * cw[(c0+0)*KC_ + k];
      acc.y += xv.y * cw[(c0+1)*KC_ + k];
      acc.z += xv.z * cw[(c0+2)*KC_ + k];
      acc.w += xv.w * cw[(c0+3)*KC_ + k];
    }
  }
  *(float4*)(xi + (size_t)t*DI_ + c0) = acc;
  *(float4*)(xrow + c0) = acc;
  __syncthreads();
  int wid = tid >> 6, lane = tid & 63;
  #pragma unroll
  for (int oi=0; oi<8; ++oi){
    int o = wid*8 + oi;
    const float* wr = (o < 16) ? (xpw + (size_t)(DS_ + o)*DI_) : (dtw + (size_t)(o-16)*DI_);
    float sum = 0.f;
    #pragma unroll
    for (int j=0;j<16;j++) sum += xrow[lane + 64*j] * wr[lane + 64*j];
    #pragma unroll
    for (int off=32; off>=1; off>>=1) sum += __shfl_down(sum, off);
    if (lane == 0) outv[o] = sum;
  }
  __syncthreads();
  if (tid < DS_){
    float d  = outv[16+tid] + dtb[tid];
    float sp = fmaxf(d, 0.f) + log1pf(expf(-fabsf(d)));
    delta[(size_t)t*DS_ + tid] = sp;
    float pr = sp * outv[tid];
    #pragma unroll
    for (int off=8; off>=1; off>>=1) pr += __shfl_down(pr, off);
    if (tid == 0) sdb[t] = pr;
  }
}

__global__ __launch_bounds__(256) void k_negA(const float* __restrict__ Alog, float* __restrict__ negA){
  int i = blockIdx.x*256 + threadIdx.x;
  negA[i] = -expf(Alog[i]);
}

__global__ __launch_bounds__(256) void k_ab(const float* __restrict__ delta,
    const float* __restrict__ sdb, const float* __restrict__ negA,
    const float* __restrict__ xi, float* __restrict__ a, float* __restrict__ bb){
  int t = blockIdx.x;
  __shared__ float dl[DS_];
  if (threadIdx.x < DS_) dl[threadIdx.x] = delta[(size_t)t*DS_ + threadIdx.x];
  __syncthreads();
  float s = sdb[t];
  int di0 = threadIdx.x << 2;
  float4 xv = *(const float4*)(xi + (size_t)t*DI_ + di0);
  float av[4];
  #pragma unroll
  for (int i=0;i<4;i++){
    const float* nA = negA + (size_t)(di0+i)*DS_;
    float sum = 0.f;
    #pragma unroll
    for (int ds=0; ds<DS_; ds++) sum += expf(dl[ds] * nA[ds]);
    av[i] = sum;
  }
  *(float4*)(a + (size_t)t*DI_ + di0) = make_float4(av[0],av[1],av[2],av[3]);
  float4 bv; bv.x=xv.x*s; bv.y=xv.y*s; bv.z=xv.z*s; bv.w=xv.w*s;
  *(float4*)(bb + (size_t)t*DI_ + di0) = bv;
}

__global__ __launch_bounds__(256) void k_scan1(const float* __restrict__ a,
    const float* __restrict__ bb, float* __restrict__ aprod, float* __restrict__ yend){
  int g  = blockIdx.x*256 + threadIdx.x;
  int di = g & (DI_-1);
  int c  = (g >> 10) & (NCHUNK-1);
  int b  = g >> 14;
  float ap = 1.f, y = 0.f;
  size_t base = ((size_t)b*S_ + (size_t)c*CHL)*DI_ + di;
  #pragma unroll 4
  for (int i=0;i<CHL;i++){
    float at = a[base + (size_t)i*DI_], bt = bb[base + (size_t)i*DI_];
    y = at*y + bt; ap *= at;
  }
  aprod[g] = ap; yend[g] = y;
}

// scan phase 2 fused with silu gating; emits yact pre-split to bf16 hi/lo
__global__ __launch_bounds__(256) void k_scan2(const float* __restrict__ a,
    const float* __restrict__ bb, const float* __restrict__ xz,
    const float* __restrict__ aprod, const float* __restrict__ yend,
    ushort* __restrict__ yh, ushort* __restrict__ yl){
  int g  = blockIdx.x*256 + threadIdx.x;
  int di = g & (DI_-1);
  int c  = (g >> 10) & (NCHUNK-1);
  int b  = g >> 14;
  float y = 0.f;
  for (int j=0;j<c;j++){
    int gg = ((b*NCHUNK + j) << 10) + di;
    y = aprod[gg]*y + yend[gg];
  }
  size_t base = ((size_t)b*S_ + (size_t)c*CHL)*DI_ + di;
  #pragma unroll 4
  for (int i=0;i<CHL;i++){
    float at = a[base + (size_t)i*DI_], bt = bb[base + (size_t)i*DI_];
    y = at*y + bt;
    float z = xz[((size_t)(b*S_ + c*CHL + i))*(2*DI_) + DI_ + di];
    float sil = z / (1.f + expf(-z));
    float v = y * sil;
    ushort hh, ll; split1(v, hh, ll);
    yh[base + (size_t)i*DI_] = hh;
    yl[base + (size_t)i*DI_] = ll;
  }
}

// ------- router -------
__global__ __launch_bounds__(64) void k_router(const float* __restrict__ xn,
    const float* __restrict__ rw, const float* __restrict__ rb,
    float* __restrict__ probs, float* __restrict__ topw, int* __restrict__ topi){
  int t = blockIdx.x, lane = threadIdx.x;
  float xv[8];
  #pragma unroll
  for (int j=0;j<8;j++) xv[j] = xn[(size_t)t*D_ + lane + 64*j];
  __shared__ float lg[E_];
  #pragma unroll
  for (int e=0;e<E_;e++){
    float s = 0.f;
    #pragma unroll
    for (int j=0;j<8;j++) s += xv[j]*rw[(size_t)e*D_ + lane + 64*j];
    #pragma unroll
    for (int off=32; off>=1; off>>=1) s += __shfl_down(s, off);
    if (lane==0) lg[e] = s + rb[e];
  }
  __syncthreads();
  if (lane==0){
    float mx = lg[0];
    #pragma unroll
    for (int e=1;e<E_;e++) mx = fmaxf(mx, lg[e]);
    float pe[E_]; float sum = 0.f;
    #pragma unroll
    for (int e=0;e<E_;e++){ pe[e] = expf(lg[e]-mx); sum += pe[e]; }
    #pragma unroll
    for (int e=0;e<E_;e++){ pe[e] /= sum; probs[(size_t)t*E_ + e] = pe[e]; }
    int i1 = 0;
    #pragma unroll
    for (int e=1;e<E_;e++) if (pe[e] > pe[i1]) i1 = e;
    int i2 = (i1==0) ? 1 : 0;
    #pragma unroll
    for (int e=0;e<E_;e++) if (e!=i1 && pe[e] > pe[i2]) i2 = e;
    float wsum = pe[i1] + pe[i2];
    topw[t*2]   = pe[i1]/wsum;
    topw[t*2+1] = pe[i2]/wsum;
    topi[t*2] = i1; topi[t*2+1] = i2;
  }
}

// ------- compaction (warp-per-expert, deterministic) + aux loss fused -------
__global__ __launch_bounds__(512) void k_compact_aux(const int* __restrict__ topi,
    const float* __restrict__ topw, const float* __restrict__ probs,
    int* __restrict__ gidx, float* __restrict__ asgw, int* __restrict__ offs,
    float* __restrict__ dst, int first){
  int e = threadIdx.x >> 6, lane = threadIdx.x & 63;
  __shared__ int counts[E_];
  __shared__ float Psh[E_];
  int cnt = 0;
  for (int c=0; c<NTOK/64; ++c){
    int t = c*64 + lane;
    bool flag = (topi[2*t]==e) || (topi[2*t+1]==e);
    unsigned long long m = __ballot(flag);
    cnt += __popcll(m);
  }
  if (lane==0) counts[e] = cnt;
  __syncthreads();
  int base = 0;
  for (int i=0;i<e;i++) base += counts[i];
  if (lane==0) offs[e] = base;
  if (threadIdx.x==0){
    int tot=0;
    for (int i=0;i<E_;i++) tot += counts[i];
    offs[E_] = tot;
  }
  int run = base;
  for (int c=0; c<NTOK/64; ++c){
    int t = c*64 + lane;
    int which = (topi[2*t]==e) ? 0 : ((topi[2*t+1]==e) ? 1 : -1);
    bool flag = which >= 0;
    unsigned long long m = __ballot(flag);
    int rank = __popcll(m & ((1ull<<lane)-1ull));
    if (flag){
      int pos = run + rank;
      gidx[pos] = t;
      asgw[pos] = topw[2*t+which];
    }
    run += __popcll(m);
  }
  // aux: warp e sums probs[:, e]
  float ps = 0.f;
  for (int c=0; c<NTOK/64; ++c){
    int t = c*64 + lane;
    ps += probs[(size_t)t*E_ + e];
  }
  #pragma unroll
  for (int off=32; off>=1; off>>=1) ps += __shfl_down(ps, off);
  if (lane==0) Psh[e] = ps;
  __syncthreads();
  if (threadIdx.x==0){
    float aux = 0.f;
    #pragma unroll
    for (int i=0;i<E_;i++){
      float P = Psh[i] * (1.0f/NTOK);
      float f = (float)counts[i] * (1.0f/(NTOK*2.0f));
      aux += f*P;
    }
    aux *= (float)E_;
    if (first) dst[0] = aux; else dst[0] += aux;
  }
}

// ---------------- host ----------------
extern "C" void kernel_launch(void* const* d_in, const int* in_sizes, int n_in,
                              void* d_out, int out_size, void* d_ws, size_t ws_size,
                              hipStream_t stream) {
  const int*   input_ids  = (const int*)  d_in[0];
  const float* tok_emb    = (const float*)d_in[1];
  const float* pos_emb    = (const float*)d_in[2];
  const float* norm1_w    = (const float*)d_in[3];
  const float* norm2_w    = (const float*)d_in[4];
  const float* in_proj_w  = (const float*)d_in[5];
  const float* conv_w     = (const float*)d_in[6];
  const float* conv_b     = (const float*)d_in[7];
  const float* x_proj_w   = (const float*)d_in[8];
  const float* dt_proj_w  = (const float*)d_in[9];
  const float* dt_proj_b  = (const float*)d_in[10];
  const float* A_log      = (const float*)d_in[11];
  const float* out_proj_w = (const float*)d_in[13];
  const float* router_w   = (const float*)d_in[14];
  const float* router_b   = (const float*)d_in[15];
  const float* w1         = (const float*)d_in[16];
  const float* b1         = (const float*)d_in[17];
  const float* w2         = (const float*)d_in[18];
  const float* b2         = (const float*)d_in[19];
  const float* final_norm = (const float*)d_in[20];
  const float* lm_head_w  = (const float*)d_in[21];
  float* out = (float*)d_out;

  // ---- workspace layout (floats) ----
  float* ws = (float*)d_ws;
  float*  x     = ws;                                    // 1,048,576
  float*  xn    = x + 1048576;                           // 1,048,576
  ushort* xnh   = (ushort*)(xn + 1048576);               // 1,048,576 us
  ushort* xnl   = xnh + 1048576;                         // 1,048,576 us
  float*  region1 = (float*)(xnl + 1048576);             // 8,388,608 f
  float*  xz    = region1;                               // 4,194,304
  float*  xi    = region1 + 4194304;                     // 2,097,152
  float*  a     = region1 + 6291456;                     // 2,097,152
  float*  bb    = region1 + 8388608;                     // 2,097,152
  ushort* yh    = (ushort*)(bb + 2097152);               // 2,097,152 us
  ushort* yl    = yh + 2097152;                          // 2,097,152 us
  float*  wsp   = (float*)(yl + 2097152);                // 8,388,608 f (weight splits)
  float*  delta = wsp + 8388608;                         // 32,768
  float*  sdb   = delta + 32768;                         // 2,048
  float*  negA  = sdb + 2048;                            // 16,384
  float*  aprod = negA + 16384;                          // 32,768
  float*  yendb = aprod + 32768;                         // 32,768
  float*  probs = yendb + 32768;                         // 16,384
  float*  topw  = probs + 16384;                         // 4,096
  float*  asgw  = topw + 4096;                           // 4,096
  int*    topi  = (int*)(asgw + 4096);                   // 4,096
  int*    gidx  = topi + 4096;                           // 4,096
  int*    offs  = gidx + 4096;                           // 16

  // aliases (dead-region reuse)
  ushort* hh  = (ushort*)region1;        // h split: 8,388,608 us each
  ushort* hl  = hh + 8388608;
  ushort* lmh = (ushort*)wsp;            // lm_head bf16: 16,384,000 us
  ushort* wh  = (ushort*)wsp;            // per-layer weight split (hi), lo follows

  float* aux_dst = out + (size_t)NTOK*VOCAB;

  k_embed<<<NTOK, 128, 0, stream>>>(input_ids, tok_emb, pos_emb, x);

  for (int l=0; l<2; ++l){
    // ---- mamba ----
    k_rmsnorm_split<<<NTOK, 128, 0, stream>>>(x, norm1_w + (size_t)l*D_, xn, xnh, xnl);
    {
      int ne = 2*DI_*D_;                 // 2,097,152
      ushort* wl_ = wh + ne;
      k_split<<<ne/1024, 256, 0, stream>>>(in_proj_w + (size_t)l*ne, wh, wl_, ne/4);
      gemm_mfma<0,4,1><<<dim3(16,16,1), 256, 0, stream>>>(xnh, xnl, wh, wl_,
          xz, nullptr, nullptr, nullptr, nullptr, nullptr, nullptr, NTOK, 2*DI_, D_);
    }
    k_convdt<<<NTOK, 256, 0, stream>>>(xz, conv_w + (size_t)l*DI_*KC_, conv_b + (size_t)l*DI_,
                                       x_proj_w + (size_t)l*2*DS_*DI_,
                                       dt_proj_w + (size_t)l*DS_*DI_, dt_proj_b + (size_t)l*DS_,
                                       xi, delta, sdb);
    k_negA<<<(DI_*DS_)/256, 256, 0, stream>>>(A_log + (size_t)l*DI_*DS_, negA);
    k_ab<<<NTOK, 256, 0, stream>>>(delta, sdb, negA, xi, a, bb);
    k_scan1<<<(NTOK*NCHUNK)/256, 256, 0, stream>>>(a, bb, aprod, yendb);
    k_scan2<<<(NTOK*NCHUNK)/256, 256, 0, stream>>>(a, bb, xz, aprod, yendb, yh, yl);
    {
      int ne = D_*DI_;                   // 524,288
      ushort* wl_ = wh + ne;
      k_split<<<ne/1024, 256, 0, stream>>>(out_proj_w + (size_t)l*ne, wh, wl_, ne/4);
      gemm_mfma<2,4,4><<<dim3(16,4,4), 256, 0, stream>>>(yh, yl, wh, wl_,
          x, nullptr, nullptr, nullptr, nullptr, nullptr, nullptr, NTOK, D_, DI_);
    }
    // ---- moe (sparse top-2) ----
    k_rmsnorm_split<<<NTOK, 128, 0, stream>>>(x, norm2_w + (size_t)l*D_, xn, xnh, xnl);
    k_router<<<NTOK, 64, 0, stream>>>(xn, router_w + (size_t)l*E_*D_, router_b + (size_t)l*E_,
                                      probs, topw, topi);
    k_compact_aux<<<1, 512, 0, stream>>>(topi, topw, probs, gidx, asgw, offs,
                                         aux_dst, l==0 ? 1 : 0);
    {
      int ne = E_*DFF_*D_;               // 8,388,608
      ushort* wl_ = wh + ne;
      k_split<<<ne/1024, 256, 0, stream>>>(w1 + (size_t)l*ne, wh, wl_, ne/4);
      gemm_mfma<1,4,1><<<dim3(16,16,8), 256, 0, stream>>>(xnh, xnl, wh, wl_,
          nullptr, hh, hl, b1 + (size_t)l*E_*DFF_, nullptr, gidx, offs, 0, DFF_, D_);
    }
    {
      int ne = E_*D_*DFF_;               // 8,388,608
      ushort* wl_ = wh + ne;
      k_split<<<ne/1024, 256, 0, stream>>>(w2 + (size_t)l*ne, wh, wl_, ne/4);
      gemm_mfma<3,4,4><<<dim3(16,4,32), 256, 0, stream>>>(hh, hl, wh, wl_,
          x, nullptr, nullptr, b2 + (size_t)l*E_*D_, asgw, gidx, offs, 0, D_, DFF_);
    }
  }

  // ---- head ----
  k_rmsnorm_split<<<NTOK, 128, 0, stream>>>(x, final_norm, xn, xnh, xnl);
  {
    int ne = VOCAB*D_;                   // 16,384,000
    k_bf16<<<ne/1024, 256, 0, stream>>>(lm_head_w, lmh, ne/4);
    gemm_mfma<0,1,1><<<dim3(16,250,1), 256, 0, stream>>>(xnh, nullptr, lmh, nullptr,
        out, nullptr, nullptr, nullptr, nullptr, nullptr, nullptr, NTOK, VOCAB, D_);
  }
}

// Round 5
// 965.192 us; speedup vs baseline: 6.8665x; 1.0836x over previous
//
#include <hip/hip_runtime.h>
#include <math.h>

#define S_    1024
#define D_    512
#define DI_   1024
#define DS_   16
#define KC_   4
#define E_    8
#define DFF_  2048
#define NTOK  2048     // B*S
#define VOCAB 32000
#define NCHUNK 16
#define CHL    64      // S_/NCHUNK
#define NSLOT 4096     // NTOK*2

typedef unsigned short ushort;
typedef unsigned int   uint;
typedef __attribute__((ext_vector_type(8))) short short8;
typedef __attribute__((ext_vector_type(4))) float f32x4;

// ---------------- helpers ----------------
__device__ __forceinline__ float gelu_sig(float x){
  // exact identity with tanh-gelu: 0.5x(1+tanh(c(x+0.044715x^3))) = x*sigmoid(2c*x + 2c*0.044715*x^3)
  float u = x*(1.5957691216057308f + 0.07135481627f*x*x);
  return x / (1.0f + expf(-u));
}
__device__ __forceinline__ ushort f2bf_rnd(float f){
  uint u = __float_as_uint(f);
  return (ushort)((u + 0x8000u) >> 16);
}
__device__ __forceinline__ float bf2f(ushort h){
  return __uint_as_float(((uint)h) << 16);
}
__device__ __forceinline__ void split1(float f, ushort& h, ushort& l){
  h = f2bf_rnd(f);
  float fh = bf2f(h);
  l = (ushort)(__float_as_uint(f - fh) >> 16);
}

// ---------------- embed ----------------
__global__ __launch_bounds__(128) void k_embed(const int* __restrict__ ids,
    const float* __restrict__ tok, const float* __restrict__ pos, float* __restrict__ x){
  int t  = blockIdx.x;
  int d4 = threadIdx.x << 2;
  int s  = t & (S_-1);
  int id = ids[t];
  float4 tv = *(const float4*)(tok + (size_t)id*D_ + d4);
  float4 pv = *(const float4*)(pos + (size_t)s*D_ + d4);
  float4 o; o.x=tv.x+pv.x; o.y=tv.y+pv.y; o.z=tv.z+pv.z; o.w=tv.w+pv.w;
  *(float4*)(x + (size_t)t*D_ + d4) = o;
}

// ------- rmsnorm -> split hi/lo; optional fused "x += sum_ks(P3[slotA]+P3[slotB])" -------
template<int ADD>
__global__ __launch_bounds__(128) void k_rmsnorm_split(float* __restrict__ x,
    const float* __restrict__ P3, const int* __restrict__ slotmap,
    const float* __restrict__ w, ushort* __restrict__ oh, ushort* __restrict__ ol){
  int t = blockIdx.x;
  int d4 = threadIdx.x << 2;
  float4 v = *(const float4*)(x + (size_t)t*D_ + d4);
  if (ADD){
    int s0 = slotmap[2*t], s1 = slotmap[2*t+1];
    #pragma unroll
    for (int ks=0; ks<4; ++ks){
      float4 p0 = *(const float4*)(P3 + ((size_t)ks*NSLOT + s0)*D_ + d4);
      float4 p1 = *(const float4*)(P3 + ((size_t)ks*NSLOT + s1)*D_ + d4);
      v.x += p0.x + p1.x; v.y += p0.y + p1.y; v.z += p0.z + p1.z; v.w += p0.w + p1.w;
    }
    *(float4*)(x + (size_t)t*D_ + d4) = v;
  }
  float ss = v.x*v.x + v.y*v.y + v.z*v.z + v.w*v.w;
  #pragma unroll
  for (int off=32; off>=1; off>>=1) ss += __shfl_down(ss, off);
  __shared__ float sred[2];
  if ((threadIdx.x & 63) == 0) sred[threadIdx.x >> 6] = ss;
  __syncthreads();
  float total = sred[0] + sred[1];
  float scale = 1.0f / sqrtf(total * (1.0f/D_) + 1e-6f);
  float4 wv = *(const float4*)(w + d4);
  float4 o; o.x=v.x*scale*wv.x; o.y=v.y*scale*wv.y; o.z=v.z*scale*wv.z; o.w=v.w*scale*wv.w;
  ushort h0,h1,h2,h3,l0,l1,l2,l3;
  split1(o.x,h0,l0); split1(o.y,h1,l1); split1(o.z,h2,l2); split1(o.w,h3,l3);
  *(uint2*)(oh + (size_t)t*D_ + d4) = make_uint2((uint)h0|((uint)h1<<16), (uint)h2|((uint)h3<<16));
  *(uint2*)(ol + (size_t)t*D_ + d4) = make_uint2((uint)l0|((uint)l1<<16), (uint)l2|((uint)l3<<16));
}

// ------- fused: x += sum_ks P2; rmsnorm -> split; router probs/top2 -------
__global__ __launch_bounds__(128) void k_rmsnorm_router(float* __restrict__ x,
    const float* __restrict__ P2, const float* __restrict__ w,
    const float* __restrict__ rw, const float* __restrict__ rb,
    ushort* __restrict__ oh, ushort* __restrict__ ol,
    float* __restrict__ probs, float* __restrict__ topw, int* __restrict__ topi){
  int t = blockIdx.x;
  int tid = threadIdx.x;
  int d4 = tid << 2;
  float4 v = *(const float4*)(x + (size_t)t*D_ + d4);
  #pragma unroll
  for (int ks=0; ks<4; ++ks){
    float4 p = *(const float4*)(P2 + (size_t)ks*NTOK*D_ + (size_t)t*D_ + d4);
    v.x += p.x; v.y += p.y; v.z += p.z; v.w += p.w;
  }
  *(float4*)(x + (size_t)t*D_ + d4) = v;
  float ss = v.x*v.x + v.y*v.y + v.z*v.z + v.w*v.w;
  #pragma unroll
  for (int off=32; off>=1; off>>=1) ss += __shfl_down(ss, off);
  __shared__ float sred[2];
  __shared__ float lg2[2][E_];
  __shared__ float lg[E_];
  if ((tid & 63) == 0) sred[tid >> 6] = ss;
  __syncthreads();
  float total = sred[0] + sred[1];
  float scale = 1.0f / sqrtf(total * (1.0f/D_) + 1e-6f);
  float4 wv = *(const float4*)(w + d4);
  float4 o; o.x=v.x*scale*wv.x; o.y=v.y*scale*wv.y; o.z=v.z*scale*wv.z; o.w=v.w*scale*wv.w;
  ushort h0,h1,h2,h3,l0,l1,l2,l3;
  split1(o.x,h0,l0); split1(o.y,h1,l1); split1(o.z,h2,l2); split1(o.w,h3,l3);
  *(uint2*)(oh + (size_t)t*D_ + d4) = make_uint2((uint)h0|((uint)h1<<16), (uint)h2|((uint)h3<<16));
  *(uint2*)(ol + (size_t)t*D_ + d4) = make_uint2((uint)l0|((uint)l1<<16), (uint)l2|((uint)l3<<16));
  // router logits
  int lane = tid & 63, wid2 = tid >> 6;
  #pragma unroll
  for (int e=0;e<E_;e++){
    const float* rr = rw + (size_t)e*D_ + d4;
    float p = o.x*rr[0] + o.y*rr[1] + o.z*rr[2] + o.w*rr[3];
    #pragma unroll
    for (int off=32; off>=1; off>>=1) p += __shfl_down(p, off);
    if (lane==0) lg2[wid2][e] = p;
  }
  __syncthreads();
  if (tid==0){
    #pragma unroll
    for (int e=0;e<E_;e++) lg[e] = lg2[0][e] + lg2[1][e] + rb[e];
    float mx = lg[0];
    #pragma unroll
    for (int e=1;e<E_;e++) mx = fmaxf(mx, lg[e]);
    float pe[E_]; float sum = 0.f;
    #pragma unroll
    for (int e=0;e<E_;e++){ pe[e] = expf(lg[e]-mx); sum += pe[e]; }
    #pragma unroll
    for (int e=0;e<E_;e++){ pe[e] /= sum; probs[(size_t)t*E_ + e] = pe[e]; }
    int i1 = 0;
    #pragma unroll
    for (int e=1;e<E_;e++) if (pe[e] > pe[i1]) i1 = e;
    int i2 = (i1==0) ? 1 : 0;
    #pragma unroll
    for (int e=0;e<E_;e++) if (e!=i1 && pe[e] > pe[i2]) i2 = e;
    float wsum = pe[i1] + pe[i2];
    topw[t*2]   = pe[i1]/wsum;
    topw[t*2+1] = pe[i2]/wsum;
    topi[t*2] = i1; topi[t*2+1] = i2;
  }
}

// ---------------- fp32 -> hi/lo split (weights) ----------------
__global__ __launch_bounds__(256) void k_split(const float* __restrict__ s,
    ushort* __restrict__ dh, ushort* __restrict__ dl, int n4){
  int i = blockIdx.x*256 + threadIdx.x;
  if (i >= n4) return;
  float4 v = ((const float4*)s)[i];
  ushort h0,h1,h2,h3,l0,l1,l2,l3;
  split1(v.x,h0,l0); split1(v.y,h1,l1); split1(v.z,h2,l2); split1(v.w,h3,l3);
  ((uint2*)dh)[i] = make_uint2((uint)h0|((uint)h1<<16), (uint)h2|((uint)h3<<16));
  ((uint2*)dl)[i] = make_uint2((uint)l0|((uint)l1<<16), (uint)l2|((uint)l3<<16));
}

// ---------------- fp32 -> bf16 hi only (lm_head weights) ----------------
__global__ __launch_bounds__(256) void k_bf16(const float* __restrict__ s,
    ushort* __restrict__ dh, int n4){
  int i = blockIdx.x*256 + threadIdx.x;
  if (i >= n4) return;
  float4 v = ((const float4*)s)[i];
  ushort h0 = f2bf_rnd(v.x), h1 = f2bf_rnd(v.y), h2 = f2bf_rnd(v.z), h3 = f2bf_rnd(v.w);
  ((uint2*)dh)[i] = make_uint2((uint)h0|((uint)h1<<16), (uint)h2|((uint)h3<<16));
}

// ============ split-bf16 MFMA GEMM on pre-split operands ============
// C[M,N] = A[M,K] @ W[N,K]^T ; A,W as bf16 hi/lo pairs (lo unused if NT==1)
// EPI 0: dense,  Cb[row*N+col] = v                 (in_proj -> xz, lm_head -> out)
// EPI 1: sparse, A row via gidx; Ch/Cl = split(gelu(v+b))     (MoE w1 -> h)
// EPI 2: dense,  Cb[ks*M*N + row*N+col] = v        (out_proj split-K partials)
// EPI 3: sparse, Cb[(ks*NSLOT+slot)*N+col] = sw*(v + b@ks0)   (MoE w2 split-K partials)
template<int EPI, int NT, int KSP>
__global__ __launch_bounds__(256, 2) void gemm_mfma(
    const ushort* __restrict__ Ah, const ushort* __restrict__ Al,
    const ushort* __restrict__ Whb, const ushort* __restrict__ Wlb,
    float* __restrict__ Cb, ushort* __restrict__ Chh, ushort* __restrict__ Chl,
    const float* __restrict__ biasb, const float* __restrict__ slotw,
    const int* __restrict__ gidx, const int* __restrict__ offs,
    int M, int N, int K)
{
  int e, ks;
  if (KSP > 1){ e = blockIdx.z / KSP; ks = blockIdx.z % KSP; }
  else        { e = blockIdx.z;       ks = 0; }
  int off = 0, cnt = M;
  if (EPI==1 || EPI==3){
    off = offs[e];
    cnt = offs[e+1] - off;
    if ((int)(blockIdx.x*128) >= cnt) return;
  }
  const size_t wbase = (size_t)((EPI==1||EPI==3) ? e : 0) * N * K;
  const ushort* Wh = Whb + wbase;
  const ushort* Wl = Wlb + wbase;
  const float* bias = (EPI==1||EPI==3) ? (biasb + (size_t)e * N) : biasb;

  __shared__ ushort As_h[128][40];
  __shared__ ushort Ws_h[128][40];
  __shared__ ushort As_l[(NT>1)?128:1][40];
  __shared__ ushort Ws_l[(NT>1)?128:1][40];

  const int tid  = threadIdx.x;
  const int row0 = blockIdx.x * 128;
  const int col0 = blockIdx.y * 128;
  const int sr = tid >> 1;
  const int sh = (tid & 1) << 4;

  int aidx;
  if (EPI==1){ int lrr = row0 + sr; if (lrr > cnt-1) lrr = cnt-1; aidx = gidx[off + lrr]; }
  else if (EPI==3){ int lrr = row0 + sr; if (lrr > cnt-1) lrr = cnt-1; aidx = off + lrr; }
  else aidx = row0 + sr;
  const ushort* arh = Ah + (size_t)aidx*K;
  const ushort* arl = Al + (size_t)aidx*K;
  const ushort* wrh = Wh + (size_t)(col0 + sr)*K;
  const ushort* wrl = Wl + (size_t)(col0 + sr)*K;

  const int lane = tid & 63;
  const int wid  = tid >> 6;
  const int wrM  = (wid >> 1) * 64;
  const int wcN  = (wid & 1) * 64;
  const int lr   = lane & 15;
  const int kq   = lane >> 4;

  f32x4 zero = {0.f, 0.f, 0.f, 0.f};
  f32x4 acc[4][4];
  #pragma unroll
  for (int i=0;i<4;i++)
    #pragma unroll
    for (int j=0;j<4;j++) acc[i][j] = zero;

  const int k0 = ks * (K / KSP);
  const int k1 = k0 + (K / KSP);

  short8 rah[2], ral[2], rwh[2], rwl[2];
  rah[0]=*(const short8*)(arh+k0+sh); rah[1]=*(const short8*)(arh+k0+sh+8);
  rwh[0]=*(const short8*)(wrh+k0+sh); rwh[1]=*(const short8*)(wrh+k0+sh+8);
  if (NT>1){
    ral[0]=*(const short8*)(arl+k0+sh); ral[1]=*(const short8*)(arl+k0+sh+8);
    rwl[0]=*(const short8*)(wrl+k0+sh); rwl[1]=*(const short8*)(wrl+k0+sh+8);
  }

  for (int kk=k0; kk<k1; kk+=32){
    __syncthreads();   // previous MFMA phase done reading LDS
    *(short8*)&As_h[sr][sh]   = rah[0];  *(short8*)&As_h[sr][sh+8] = rah[1];
    *(short8*)&Ws_h[sr][sh]   = rwh[0];  *(short8*)&Ws_h[sr][sh+8] = rwh[1];
    if (NT>1){
      *(short8*)&As_l[sr][sh]   = ral[0];  *(short8*)&As_l[sr][sh+8] = ral[1];
      *(short8*)&Ws_l[sr][sh]   = rwl[0];  *(short8*)&Ws_l[sr][sh+8] = rwl[1];
    }
    if (kk + 32 < k1){
      int kn = kk + 32 + sh;
      rah[0]=*(const short8*)(arh+kn); rah[1]=*(const short8*)(arh+kn+8);
      rwh[0]=*(const short8*)(wrh+kn); rwh[1]=*(const short8*)(wrh+kn+8);
      if (NT>1){
        ral[0]=*(const short8*)(arl+kn); ral[1]=*(const short8*)(arl+kn+8);
        rwl[0]=*(const short8*)(wrl+kn); rwl[1]=*(const short8*)(wrl+kn+8);
      }
    }
    __syncthreads();

    short8 fah[4], fal[4], fbh[4], fbl[4];
    #pragma unroll
    for (int f=0; f<4; ++f){
      int rA = wrM + f*16 + lr;
      fah[f] = *(const short8*)&As_h[rA][kq*8];
      int rB = wcN + f*16 + lr;
      fbh[f] = *(const short8*)&Ws_h[rB][kq*8];
      if (NT>1){
        fal[f] = *(const short8*)&As_l[rA][kq*8];
        fbl[f] = *(const short8*)&Ws_l[rB][kq*8];
      }
    }
    #pragma unroll
    for (int i=0;i<4;i++)
      #pragma unroll
      for (int j=0;j<4;j++){
        f32x4 c = acc[i][j];
        if (NT==4) c = __builtin_amdgcn_mfma_f32_16x16x32_bf16(fal[i], fbl[j], c, 0,0,0);
        if (NT>1){
          c = __builtin_amdgcn_mfma_f32_16x16x32_bf16(fal[i], fbh[j], c, 0,0,0);
          c = __builtin_amdgcn_mfma_f32_16x16x32_bf16(fah[i], fbl[j], c, 0,0,0);
        }
        c = __builtin_amdgcn_mfma_f32_16x16x32_bf16(fah[i], fbh[j], c, 0,0,0);
        acc[i][j] = c;
      }
  }

  float bj[4];
  if (EPI==1 || EPI==3){
    #pragma unroll
    for (int j=0;j<4;j++) bj[j] = bias[col0 + wcN + j*16 + lr];
  }
  #pragma unroll
  for (int i=0;i<4;i++){
    #pragma unroll
    for (int jj=0;jj<4;jj++){
      int rt   = wrM + i*16 + kq*4 + jj;
      int grow = row0 + rt;
      if (EPI==0){
        float* cr = Cb + (size_t)grow*N + col0 + wcN + lr;
        #pragma unroll
        for (int j=0;j<4;j++) cr[j*16] = acc[i][j][jj];
      } else if (EPI==2){
        float* cr = Cb + (size_t)ks*M*N + (size_t)grow*N + col0 + wcN + lr;
        #pragma unroll
        for (int j=0;j<4;j++) cr[j*16] = acc[i][j][jj];
      } else if (EPI==1){
        if (grow < cnt){
          int slot = off + grow;
          size_t base = (size_t)slot*N + col0 + wcN + lr;
          #pragma unroll
          for (int j=0;j<4;j++){
            float g = gelu_sig(acc[i][j][jj] + bj[j]);
            ushort hh, ll; split1(g, hh, ll);
            Chh[base + j*16] = hh; Chl[base + j*16] = ll;
          }
        }
      } else {
        if (grow < cnt){
          int slot = off + grow;
          float sw = slotw[slot];
          float* cr = Cb + ((size_t)ks*NSLOT + slot)*N + col0 + wcN + lr;
          #pragma unroll
          for (int j=0;j<4;j++){
            float v = acc[i][j][jj];
            if (ks==0) v += bj[j];
            cr[j*16] = sw*v;
          }
        }
      }
    }
  }
}

// ------ fused: conv(KC=4)+bias ; x_dbl (B,delta,sdb) ; a,b tensors ------
__global__ __launch_bounds__(256) void k_convab(const float* __restrict__ xz,
    const float* __restrict__ cw, const float* __restrict__ cb,
    const float* __restrict__ xpw, const float* __restrict__ dtw,
    const float* __restrict__ dtb, const float* __restrict__ negA,
    float* __restrict__ a, float* __restrict__ bb){
  int t = blockIdx.x;
  int b = t >> 10, s = t & (S_-1);
  int tid = threadIdx.x;
  int c0 = tid << 2;
  __shared__ float xrow[DI_];
  __shared__ float outv[32];
  __shared__ float dl[DS_+1];
  float4 acc = *(const float4*)(cb + c0);
  #pragma unroll
  for (int k=0;k<KC_;k++){
    int ss = s - (KC_-1) + k;
    if (ss >= 0){
      float4 xv = *(const float4*)(xz + ((size_t)(b*S_+ss))*(2*DI_) + c0);
      acc.x += xv.x * cw[(c0+0)*KC_ + k];
      acc.y += xv.y * cw[(c0+1)*KC_ + k];
      acc.z += xv.z * cw[(c0+2)*KC_ + k];
      acc.w += xv.w * cw[(c0+3)*KC_ + k];
    }
  }
  *(float4*)(xrow + c0) = acc;
  __syncthreads();
  int wid = tid >> 6, lane = tid & 63;
  #pragma unroll
  for (int oi=0; oi<8; ++oi){
    int o = wid*8 + oi;
    const float* wr = (o < 16) ? (xpw + (size_t)(DS_ + o)*DI_) : (dtw + (size_t)(o-16)*DI_);
    float sum = 0.f;
    #pragma unroll
    for (int j=0;j<16;j++) sum += xrow[lane + 64*j] * wr[lane + 64*j];
    #pragma unroll
    for (int off=32; off>=1; off>>=1) sum += __shfl_down(sum, off);
    if (lane == 0) outv[o] = sum;
  }
  __syncthreads();
  if (tid < DS_){
    float d  = outv[16+tid] + dtb[tid];
    float sp = fmaxf(d, 0.f) + log1pf(expf(-fabsf(d)));
    dl[tid] = sp;
    float pr = sp * outv[tid];
    #pragma unroll
    for (int off=8; off>=1; off>>=1) pr += __shfl_down(pr, off);
    if (tid == 0) dl[DS_] = pr;
  }
  __syncthreads();
  float sdbv = dl[DS_];
  float av[4];
  #pragma unroll
  for (int i=0;i<4;i++){
    const float* nA = negA + (size_t)(c0+i)*DS_;
    float sum = 0.f;
    #pragma unroll
    for (int ds=0; ds<DS_; ds++) sum += expf(dl[ds] * nA[ds]);
    av[i] = sum;
  }
  *(float4*)(a + (size_t)t*DI_ + c0) = make_float4(av[0],av[1],av[2],av[3]);
  float4 bv; bv.x=acc.x*sdbv; bv.y=acc.y*sdbv; bv.z=acc.z*sdbv; bv.w=acc.w*sdbv;
  *(float4*)(bb + (size_t)t*DI_ + c0) = bv;
}

__global__ __launch_bounds__(256) void k_negA(const float* __restrict__ Alog, float* __restrict__ negA){
  int i = blockIdx.x*256 + threadIdx.x;
  negA[i] = -expf(Alog[i]);
}

__global__ __launch_bounds__(256) void k_scan1(const float* __restrict__ a,
    const float* __restrict__ bb, float* __restrict__ aprod, float* __restrict__ yend){
  int g  = blockIdx.x*256 + threadIdx.x;
  int di = g & (DI_-1);
  int c  = (g >> 10) & (NCHUNK-1);
  int b  = g >> 14;
  float ap = 1.f, y = 0.f;
  size_t base = ((size_t)b*S_ + (size_t)c*CHL)*DI_ + di;
  #pragma unroll 4
  for (int i=0;i<CHL;i++){
    float at = a[base + (size_t)i*DI_], bt = bb[base + (size_t)i*DI_];
    y = at*y + bt; ap *= at;
  }
  aprod[g] = ap; yend[g] = y;
}

// scan phase 2 fused with silu gating; emits yact pre-split to bf16 hi/lo
__global__ __launch_bounds__(256) void k_scan2(const float* __restrict__ a,
    const float* __restrict__ bb, const float* __restrict__ xz,
    const float* __restrict__ aprod, const float* __restrict__ yend,
    ushort* __restrict__ yh, ushort* __restrict__ yl){
  int g  = blockIdx.x*256 + threadIdx.x;
  int di = g & (DI_-1);
  int c  = (g >> 10) & (NCHUNK-1);
  int b  = g >> 14;
  float y = 0.f;
  for (int j=0;j<c;j++){
    int gg = ((b*NCHUNK + j) << 10) + di;
    y = aprod[gg]*y + yend[gg];
  }
  size_t base = ((size_t)b*S_ + (size_t)c*CHL)*DI_ + di;
  #pragma unroll 4
  for (int i=0;i<CHL;i++){
    float at = a[base + (size_t)i*DI_], bt = bb[base + (size_t)i*DI_];
    y = at*y + bt;
    float z = xz[((size_t)(b*S_ + c*CHL + i))*(2*DI_) + DI_ + di];
    float sil = z / (1.f + expf(-z));
    float v = y * sil;
    ushort hh, ll; split1(v, hh, ll);
    yh[base + (size_t)i*DI_] = hh;
    yl[base + (size_t)i*DI_] = ll;
  }
}

// ------- compaction (warp-per-expert, deterministic) + aux loss fused -------
__global__ __launch_bounds__(512) void k_compact_aux(const int* __restrict__ topi,
    const float* __restrict__ topw, const float* __restrict__ probs,
    int* __restrict__ gidx, float* __restrict__ asgw, int* __restrict__ slotmap,
    int* __restrict__ offs, float* __restrict__ dst, int first){
  int e = threadIdx.x >> 6, lane = threadIdx.x & 63;
  __shared__ int counts[E_];
  __shared__ float Psh[E_];
  int cnt = 0;
  for (int c=0; c<NTOK/64; ++c){
    int t = c*64 + lane;
    bool flag = (topi[2*t]==e) || (topi[2*t+1]==e);
    unsigned long long m = __ballot(flag);
    cnt += __popcll(m);
  }
  if (lane==0) counts[e] = cnt;
  __syncthreads();
  int base = 0;
  for (int i=0;i<e;i++) base += counts[i];
  if (lane==0) offs[e] = base;
  if (threadIdx.x==0){
    int tot=0;
    for (int i=0;i<E_;i++) tot += counts[i];
    offs[E_] = tot;
  }
  int run = base;
  for (int c=0; c<NTOK/64; ++c){
    int t = c*64 + lane;
    int which = (topi[2*t]==e) ? 0 : ((topi[2*t+1]==e) ? 1 : -1);
    bool flag = which >= 0;
    unsigned long long m = __ballot(flag);
    int rank = __popcll(m & ((1ull<<lane)-1ull));
    if (flag){
      int pos = run + rank;
      gidx[pos] = t;
      asgw[pos] = topw[2*t+which];
      slotmap[2*t+which] = pos;
    }
    run += __popcll(m);
  }
  // aux: warp e sums probs[:, e]
  float ps = 0.f;
  for (int c=0; c<NTOK/64; ++c){
    int t = c*64 + lane;
    ps += probs[(size_t)t*E_ + e];
  }
  #pragma unroll
  for (int off=32; off>=1; off>>=1) ps += __shfl_down(ps, off);
  if (lane==0) Psh[e] = ps;
  __syncthreads();
  if (threadIdx.x==0){
    float aux = 0.f;
    #pragma unroll
    for (int i=0;i<E_;i++){
      float P = Psh[i] * (1.0f/NTOK);
      float f = (float)counts[i] * (1.0f/(NTOK*2.0f));
      aux += f*P;
    }
    aux *= (float)E_;
    if (first) dst[0] = aux; else dst[0] += aux;
  }
}

// ---------------- host ----------------
extern "C" void kernel_launch(void* const* d_in, const int* in_sizes, int n_in,
                              void* d_out, int out_size, void* d_ws, size_t ws_size,
                              hipStream_t stream) {
  const int*   input_ids  = (const int*)  d_in[0];
  const float* tok_emb    = (const float*)d_in[1];
  const float* pos_emb    = (const float*)d_in[2];
  const float* norm1_w    = (const float*)d_in[3];
  const float* norm2_w    = (const float*)d_in[4];
  const float* in_proj_w  = (const float*)d_in[5];
  const float* conv_w     = (const float*)d_in[6];
  const float* conv_b     = (const float*)d_in[7];
  const float* x_proj_w   = (const float*)d_in[8];
  const float* dt_proj_w  = (const float*)d_in[9];
  const float* dt_proj_b  = (const float*)d_in[10];
  const float* A_log      = (const float*)d_in[11];
  const float* out_proj_w = (const float*)d_in[13];
  const float* router_w   = (const float*)d_in[14];
  const float* router_b   = (const float*)d_in[15];
  const float* w1         = (const float*)d_in[16];
  const float* b1         = (const float*)d_in[17];
  const float* w2         = (const float*)d_in[18];
  const float* b2         = (const float*)d_in[19];
  const float* final_norm = (const float*)d_in[20];
  const float* lm_head_w  = (const float*)d_in[21];
  float* out = (float*)d_out;

  // ---- workspace layout (float offsets; ws is 1 GiB) ----
  float* f0 = (float*)d_ws;
  float*  x    = f0;                                   // 1,048,576
  ushort* xnh  = (ushort*)(f0 + 1048576);              // 1,048,576 us
  ushort* xnl  = xnh + 1048576;                        //
  float*  xz   = f0 + 2097152;                         // 4,194,304
  float*  a    = f0 + 6291456;                         // 2,097,152
  float*  bb   = f0 + 8388608;                         // 2,097,152
  ushort* yh   = (ushort*)(f0 + 10485760);             // 2,097,152 us
  ushort* yl   = yh + 2097152;                         //
  float*  wsp  = f0 + 12582912;                        // 16,777,216 (w1 hi/lo + w2 hi/lo)
  float*  P2   = f0 + 29360128;                        // 4,194,304  (4 x NTOK x D)
  float*  P3   = f0 + 33554432;                        // 8,388,608  (4 x NSLOT x D)
  float*  negA = f0 + 41943040;                        // 16,384
  float*  aprod= negA + 16384;                         // 32,768
  float*  yendb= aprod + 32768;                        // 32,768
  float*  probs= yendb + 32768;                        // 16,384
  float*  topw = probs + 16384;                        // 4,096
  float*  asgw = topw + 4096;                          // 4,096
  int*    topi = (int*)(asgw + 4096);                  // 4,096
  int*    gidx = topi + 4096;                          // 4,096
  int*    slotmap = gidx + 4096;                       // 4,096
  int*    offs = slotmap + 4096;                       // 16

  // aliases over dead regions
  ushort* hh  = (ushort*)xz;            // h split: 8,388,608 us each (over xz+a+bb, dead after scan2)
  ushort* hl  = hh + 8388608;
  ushort* lmh = (ushort*)wsp;           // lm_head bf16: 16,384,000 us
  ushort* w1h = (ushort*)wsp;           // w1 split hi/lo
  ushort* w1l = w1h + 8388608;
  ushort* w2h = w1l + 8388608;          // w2 split hi/lo
  ushort* w2l = w2h + 8388608;
  ushort* wph = (ushort*)wsp;           // small per-projection splits (in/out_proj)

  float* aux_dst = out + (size_t)NTOK*VOCAB;

  k_embed<<<NTOK, 128, 0, stream>>>(input_ids, tok_emb, pos_emb, x);

  for (int l=0; l<2; ++l){
    // ---- mamba ----
    if (l == 0)
      k_rmsnorm_split<0><<<NTOK, 128, 0, stream>>>(x, nullptr, nullptr,
          norm1_w + (size_t)l*D_, xnh, xnl);
    else
      k_rmsnorm_split<1><<<NTOK, 128, 0, stream>>>(x, P3, slotmap,
          norm1_w + (size_t)l*D_, xnh, xnl);
    {
      int ne = 2*DI_*D_;                 // 2,097,152
      ushort* wl_ = wph + ne;
      k_split<<<ne/1024, 256, 0, stream>>>(in_proj_w + (size_t)l*ne, wph, wl_, ne/4);
      gemm_mfma<0,3,1><<<dim3(16,16,1), 256, 0, stream>>>(xnh, xnl, wph, wl_,
          xz, nullptr, nullptr, nullptr, nullptr, nullptr, nullptr, NTOK, 2*DI_, D_);
    }
    k_negA<<<(DI_*DS_)/256, 256, 0, stream>>>(A_log + (size_t)l*DI_*DS_, negA);
    k_convab<<<NTOK, 256, 0, stream>>>(xz, conv_w + (size_t)l*DI_*KC_, conv_b + (size_t)l*DI_,
                                       x_proj_w + (size_t)l*2*DS_*DI_,
                                       dt_proj_w + (size_t)l*DS_*DI_, dt_proj_b + (size_t)l*DS_,
                                       negA, a, bb);
    k_scan1<<<(NTOK*NCHUNK)/256, 256, 0, stream>>>(a, bb, aprod, yendb);
    k_scan2<<<(NTOK*NCHUNK)/256, 256, 0, stream>>>(a, bb, xz, aprod, yendb, yh, yl);
    {
      int ne = D_*DI_;                   // 524,288
      ushort* wl_ = wph + ne;
      k_split<<<ne/1024, 256, 0, stream>>>(out_proj_w + (size_t)l*ne, wph, wl_, ne/4);
      gemm_mfma<2,3,4><<<dim3(16,4,4), 256, 0, stream>>>(yh, yl, wph, wl_,
          P2, nullptr, nullptr, nullptr, nullptr, nullptr, nullptr, NTOK, D_, DI_);
    }
    // ---- moe (sparse top-2): x += sum P2 fused into rmsnorm+router ----
    k_rmsnorm_router<<<NTOK, 128, 0, stream>>>(x, P2, norm2_w + (size_t)l*D_,
        router_w + (size_t)l*E_*D_, router_b + (size_t)l*E_,
        xnh, xnl, probs, topw, topi);
    k_compact_aux<<<1, 512, 0, stream>>>(topi, topw, probs, gidx, asgw, slotmap, offs,
                                         aux_dst, l==0 ? 1 : 0);
    {
      int ne = E_*DFF_*D_;               // 8,388,608
      k_split<<<ne/1024, 256, 0, stream>>>(w1 + (size_t)l*ne, w1h, w1l, ne/4);
      k_split<<<ne/1024, 256, 0, stream>>>(w2 + (size_t)l*ne, w2h, w2l, ne/4);
      gemm_mfma<1,3,1><<<dim3(16,16,8), 256, 0, stream>>>(xnh, xnl, w1h, w1l,
          nullptr, hh, hl, b1 + (size_t)l*E_*DFF_, nullptr, gidx, offs, 0, DFF_, D_);
      gemm_mfma<3,3,4><<<dim3(16,4,32), 256, 0, stream>>>(hh, hl, w2h, w2l,
          P3, nullptr, nullptr, b2 + (size_t)l*E_*D_, asgw, gidx, offs, 0, D_, DFF_);
    }
  }

  // ---- head (x += last layer's P3 fused into final norm) ----
  k_rmsnorm_split<1><<<NTOK, 128, 0, stream>>>(x, P3, slotmap, final_norm, xnh, xnl);
  {
    int ne = VOCAB*D_;                   // 16,384,000
    k_bf16<<<ne/1024, 256, 0, stream>>>(lm_head_w, lmh, ne/4);
    gemm_mfma<0,1,1><<<dim3(16,250,1), 256, 0, stream>>>(xnh, nullptr, lmh, nullptr,
        out, nullptr, nullptr, nullptr, nullptr, nullptr, nullptr, NTOK, VOCAB, D_);
  }
}